// Round 16
// baseline (287.955 us; speedup 1.0000x reference)
//
#include <hip/hip_runtime.h>
#include <hip/hip_cooperative_groups.h>
#include <math.h>

namespace cg = cooperative_groups;

// B=64, N_in=1152, K_in=8, N_out=64, K_out=16, ITER=3
// Fused cooperative kernel (xform + 3 passes + 3 reduces, grid.sync between),
// W bf16-HI only, r15 phase bodies. __launch_bounds__(1024,4) -> 128-VGPR cap
// (r12's failure was (1024,1) -> 64-VGPR collapse + spill).

#define CTI 18        // i per chunk
#define IPB 2         // i per buffer step
#define NSTEP 9       // CTI / IPB
#define CNCH 64       // 1152 / CTI

typedef __attribute__((ext_vector_type(8))) short short8v;
typedef __attribute__((ext_vector_type(8))) unsigned short ushort8v;
typedef __attribute__((ext_vector_type(4))) float f32x4;

typedef const __attribute__((address_space(1))) unsigned int gu32;
typedef __attribute__((address_space(3))) unsigned int lu32;

__device__ __forceinline__ unsigned short f2bf(float f) {   // RTNE
    unsigned u = __builtin_bit_cast(unsigned, f);
    u = u + 0x7FFFu + ((u >> 16) & 1u);
    return (unsigned short)(u >> 16);
}
__device__ __forceinline__ float bf2f(unsigned short h) {
    unsigned u = ((unsigned)h) << 16;
    return __builtin_bit_cast(float, u);
}
__device__ __forceinline__ float lo16f(unsigned u) {
    return __builtin_bit_cast(float, u << 16);
}
__device__ __forceinline__ float hi16f(unsigned u) {
    return __builtin_bit_cast(float, u & 0xFFFF0000u);
}

// ---------------------------- fused cooperative kernel ----------------------------
__global__ __launch_bounds__(1024, 4)
void caps_fused(const float* __restrict__ W, const float* __restrict__ x,
                unsigned short* __restrict__ Wp, unsigned short* __restrict__ xp,
                float* __restrict__ Vfp, unsigned short* __restrict__ spart,
                float* __restrict__ out) {
    cg::grid_group grid = cg::this_grid();

    __shared__ alignas(16) unsigned short wlds[2][IPB * 8192];  // 64 KB (hi only)
    __shared__ float zbuf[2][IPB][256];

    const int t = threadIdx.x;
    const int wv = t >> 6, l = t & 63;
    const int btile = blockIdx.x >> 6, chunk = blockIdx.x & 63;
    const int g = l >> 4, b15 = l & 15;
    const int o0 = wv * 4;
    const int i0 = chunk * CTI;
    const bool act = (g < 2);
    const short8v z8 = {0, 0, 0, 0, 0, 0, 0, 0};

    // ---------------- phase X: W -> Wp (hi only), x -> xp (hi/lo) ----------------
    {
        const int gtid = blockIdx.x * 1024 + t;
        for (int idx = gtid; idx < 1152 * 64 * 16; idx += 256 * 1024) {
            int k = idx & 15, o = (idx >> 4) & 63, i = idx >> 10;
            const float4* src = (const float4*)(W + (((size_t)o * 1152 + i) * 16 + k) * 8);
            float4 v0 = src[0], v1 = src[1];
            float vf[8] = {v0.x, v0.y, v0.z, v0.w, v1.x, v1.y, v1.z, v1.w};
            ushort8v hi;
            #pragma unroll
            for (int j = 0; j < 8; ++j) hi[j] = f2bf(vf[j]);
            *reinterpret_cast<ushort8v*>(Wp + (((size_t)i * 64 + o) * 16 + k) * 8) = hi;
        }
        for (int idx = gtid; idx < 1152 * 64; idx += 256 * 1024) {
            int b = idx & 63, i = idx >> 6;
            const float4* src = (const float4*)(x + ((size_t)b * 1152 + i) * 8);
            float4 v0 = src[0], v1 = src[1];
            float vf[8] = {v0.x, v0.y, v0.z, v0.w, v1.x, v1.y, v1.z, v1.w};
            ushort8v hi, lo;
            #pragma unroll
            for (int j = 0; j < 8; ++j) {
                unsigned short h = f2bf(vf[j]);
                hi[j] = h;
                lo[j] = f2bf(vf[j] - bf2f(h));
            }
            size_t base = ((size_t)i * 2) * 512 + (size_t)b * 8;
            *reinterpret_cast<ushort8v*>(xp + base)       = hi;
            *reinterpret_cast<ushort8v*>(xp + base + 512) = lo;
        }
    }

    #define STAGE2(buf, ibase)                                                    \
    {                                                                             \
        const ushort8v* srcb = reinterpret_cast<const ushort8v*>(                 \
            Wp + (size_t)(ibase) * 8192);                                         \
        _Pragma("unroll")                                                         \
        for (int r = 0; r < 2; ++r)                                               \
            __builtin_amdgcn_global_load_lds(                                     \
                (gu32*)(srcb + (r * 1024 + wv * 64 + l)),                         \
                (lu32*)&wlds[buf][(size_t)(r * 1024 + wv * 64) * 8], 16, 0, 0);   \
    }
    #define LOADB(i) (*reinterpret_cast<const short8v*>(                          \
        xp + (((size_t)(i) * 2 + g) * 64 + btile * 16 + b15) * 8))

    #define CAPS_PASS(R)                                                          \
    {                                                                             \
        uint2 vpk[4];                                                             \
        if (R) {                                                                  \
            _Pragma("unroll")                                                     \
            for (int oo = 0; oo < 4; ++oo) {                                      \
                f32x4 Vf = *reinterpret_cast<const f32x4*>(                       \
                    Vfp + (((size_t)btile * 64 + o0 + oo) * 64 + l) * 4);         \
                vpk[oo].x = (unsigned)f2bf(Vf[0]) | ((unsigned)f2bf(Vf[1]) << 16);\
                vpk[oo].y = (unsigned)f2bf(Vf[2]) | ((unsigned)f2bf(Vf[3]) << 16);\
            }                                                                     \
        }                                                                         \
        f32x4 s[4];                                                               \
        _Pragma("unroll")                                                         \
        for (int oo = 0; oo < 4; ++oo) s[oo] = (f32x4){0.f, 0.f, 0.f, 0.f};       \
        STAGE2(0, i0);                                                            \
        short8v Bf0 = z8, Bf1 = z8;                                               \
        if (act) { Bf0 = LOADB(i0); Bf1 = LOADB(i0 + 1); }                        \
        __syncthreads();                                                          \
        const int aoffbase = b15 * 8;                                             \
        int cur = 0;                                                              \
        for (int st = 0; st < NSTEP; ++st) {                                      \
            short8v Bn0 = Bf0, Bn1 = Bf1;                                         \
            if (st + 1 < NSTEP) {                                                 \
                STAGE2(cur ^ 1, i0 + (st + 1) * IPB);                             \
                if (act) {                                                        \
                    Bn0 = LOADB(i0 + (st + 1) * IPB);                             \
                    Bn1 = LOADB(i0 + (st + 1) * IPB + 1);                         \
                }                                                                 \
            }                                                                     \
            if (!R) {                                                             \
                _Pragma("unroll")                                                 \
                for (int oo = 0; oo < 4; ++oo) {                                  \
                    short8v Af0 = z8, Af1 = z8;                                   \
                    if (act) {                                                    \
                        const int ao = (o0 + oo) * 128 + aoffbase;                \
                        Af0 = *reinterpret_cast<const short8v*>(&wlds[cur][0] + ao);    \
                        Af1 = *reinterpret_cast<const short8v*>(&wlds[cur][8192] + ao); \
                    }                                                             \
                    s[oo] = __builtin_amdgcn_mfma_f32_16x16x32_bf16(Af0, Bf0, s[oo], 0, 0, 0); \
                    s[oo] = __builtin_amdgcn_mfma_f32_16x16x32_bf16(Af1, Bf1, s[oo], 0, 0, 0); \
                }                                                                 \
                __syncthreads();                                                  \
            } else {                                                              \
                f32x4 u[IPB][4];                                                  \
                float lg[IPB][4];                                                 \
                float Zp0 = 0.f, Zp1 = 0.f;                                       \
                _Pragma("unroll")                                                 \
                for (int oo = 0; oo < 4; ++oo) {                                  \
                    short8v Af0 = z8, Af1 = z8;                                   \
                    if (act) {                                                    \
                        const int ao = (o0 + oo) * 128 + aoffbase;                \
                        Af0 = *reinterpret_cast<const short8v*>(&wlds[cur][0] + ao);    \
                        Af1 = *reinterpret_cast<const short8v*>(&wlds[cur][8192] + ao); \
                    }                                                             \
                    f32x4 zz = {0.f, 0.f, 0.f, 0.f};                              \
                    u[0][oo] = __builtin_amdgcn_mfma_f32_16x16x32_bf16(Af0, Bf0, zz, 0, 0, 0); \
                    u[1][oo] = __builtin_amdgcn_mfma_f32_16x16x32_bf16(Af1, Bf1, zz, 0, 0, 0); \
                    float p0 = u[0][oo][0] * lo16f(vpk[oo].x);                    \
                    p0 = fmaf(u[0][oo][1], hi16f(vpk[oo].x), p0);                 \
                    p0 = fmaf(u[0][oo][2], lo16f(vpk[oo].y), p0);                 \
                    p0 = fmaf(u[0][oo][3], hi16f(vpk[oo].y), p0);                 \
                    float p1 = u[1][oo][0] * lo16f(vpk[oo].x);                    \
                    p1 = fmaf(u[1][oo][1], hi16f(vpk[oo].x), p1);                 \
                    p1 = fmaf(u[1][oo][2], lo16f(vpk[oo].y), p1);                 \
                    p1 = fmaf(u[1][oo][3], hi16f(vpk[oo].y), p1);                 \
                    p0 += __shfl_xor(p0, 16, 64);  p1 += __shfl_xor(p1, 16, 64);  \
                    p0 += __shfl_xor(p0, 32, 64);  p1 += __shfl_xor(p1, 32, 64);  \
                    float e0 = __expf(p0), e1 = __expf(p1);                       \
                    lg[0][oo] = e0; lg[1][oo] = e1;                               \
                    Zp0 += e0; Zp1 += e1;                                         \
                }                                                                 \
                if (l < 16) {                                                     \
                    zbuf[st & 1][0][wv * 16 + l] = Zp0;                           \
                    zbuf[st & 1][1][wv * 16 + l] = Zp1;                           \
                }                                                                 \
                __syncthreads();                                                  \
                float Z0 = zbuf[st & 1][0][b15];                                  \
                float Z1 = zbuf[st & 1][1][b15];                                  \
                _Pragma("unroll")                                                 \
                for (int w2 = 1; w2 < 16; ++w2) {                                 \
                    Z0 += zbuf[st & 1][0][w2 * 16 + b15];                         \
                    Z1 += zbuf[st & 1][1][w2 * 16 + b15];                         \
                }                                                                 \
                float rz0 = 1.0f / Z0, rz1 = 1.0f / Z1;                           \
                _Pragma("unroll")                                                 \
                for (int oo = 0; oo < 4; ++oo) {                                  \
                    float c0 = lg[0][oo] * rz0;                                   \
                    float c1 = lg[1][oo] * rz1;                                   \
                    s[oo][0] = fmaf(c0, u[0][oo][0], fmaf(c1, u[1][oo][0], s[oo][0])); \
                    s[oo][1] = fmaf(c0, u[0][oo][1], fmaf(c1, u[1][oo][1], s[oo][1])); \
                    s[oo][2] = fmaf(c0, u[0][oo][2], fmaf(c1, u[1][oo][2], s[oo][2])); \
                    s[oo][3] = fmaf(c0, u[0][oo][3], fmaf(c1, u[1][oo][3], s[oo][3])); \
                }                                                                 \
            }                                                                     \
            Bf0 = Bn0; Bf1 = Bn1;                                                 \
            cur ^= 1;                                                             \
        }                                                                         \
        const float fin = (R) ? 1.0f : (1.0f / 64.0f);                            \
        _Pragma("unroll")                                                         \
        for (int oo = 0; oo < 4; ++oo) {                                          \
            f32x4 vv = s[oo] * fin;                                               \
            uint2 pk;                                                             \
            pk.x = (unsigned)f2bf(vv[0]) | ((unsigned)f2bf(vv[1]) << 16);         \
            pk.y = (unsigned)f2bf(vv[2]) | ((unsigned)f2bf(vv[3]) << 16);         \
            *reinterpret_cast<uint2*>(spart +                                     \
                ((((size_t)chunk * 4 + btile) * 64 + (o0 + oo)) * 64 + l) * 4) = pk; \
        }                                                                         \
    }

    #define REDUCE_PHASE(MODE)                                                    \
    {                                                                             \
        f32x4* red = reinterpret_cast<f32x4*>(&wlds[0][0]);                       \
        const int cq = t >> 6;                                                    \
        const int pair = blockIdx.x;                                              \
        const int rb = pair >> 6, ro = pair & 63;                                 \
        f32x4 acc = {0.f, 0.f, 0.f, 0.f};                                         \
        const unsigned short* rbase = spart + (((size_t)rb * 64 + ro) * 64 + l) * 4; \
        for (int c = cq * (CNCH/16); c < (cq + 1) * (CNCH/16); ++c) {             \
            uint2 w_ = *reinterpret_cast<const uint2*>(rbase + (size_t)c * 65536);\
            acc[0] += lo16f(w_.x); acc[1] += hi16f(w_.x);                         \
            acc[2] += lo16f(w_.y); acc[3] += hi16f(w_.y);                         \
        }                                                                         \
        red[t] = acc;                                                             \
        __syncthreads();                                                          \
        if (cq == 0) {                                                            \
            _Pragma("unroll")                                                     \
            for (int w2 = 1; w2 < 16; ++w2) acc += red[w2 * 64 + l];              \
            float n2 = acc[0]*acc[0] + acc[1]*acc[1] + acc[2]*acc[2] + acc[3]*acc[3]; \
            n2 += __shfl_xor(n2, 16, 64);                                         \
            n2 += __shfl_xor(n2, 32, 64);                                         \
            const float scale = n2 / (1.0f + n2) / sqrtf(n2 + 1e-7f);             \
            f32x4 v = acc * scale;                                                \
            float* vp = Vfp + (((size_t)rb * 64 + ro) * 64 + l) * 4;              \
            if (MODE == 0) {                                                      \
                *reinterpret_cast<f32x4*>(vp) = v;                                \
            } else if (MODE == 1) {                                               \
                f32x4 old = *reinterpret_cast<const f32x4*>(vp);                  \
                *reinterpret_cast<f32x4*>(vp) = old + v;                          \
            } else {                                                              \
                const int b_ = rb * 16 + (l & 15), gq = l >> 4;                   \
                *reinterpret_cast<f32x4*>(out + (((size_t)b_ * 64 + ro) * 16 + gq * 4)) = v; \
            }                                                                     \
        }                                                                         \
    }

    grid.sync();          // Wp/xp complete
    CAPS_PASS(0)
    grid.sync();          // spart complete
    REDUCE_PHASE(0)
    grid.sync();          // Vfp complete
    CAPS_PASS(1)
    grid.sync();
    REDUCE_PHASE(1)
    grid.sync();
    CAPS_PASS(1)
    grid.sync();
    REDUCE_PHASE(2)

    #undef STAGE2
    #undef LOADB
    #undef CAPS_PASS
    #undef REDUCE_PHASE
}

// ---------------------- multi-dispatch fallback (round-15, proven) ----------------------
__global__ __launch_bounds__(256)
void xform(const float* __restrict__ W, const float* __restrict__ x,
           unsigned short* __restrict__ Wp, unsigned short* __restrict__ xpp) {
    const int bid = blockIdx.x;
    if (bid < 4608) {
        int tid = bid * 256 + threadIdx.x;
        int k = tid & 15, o = (tid >> 4) & 63, i = tid >> 10;
        const float4* src = (const float4*)(W + (((size_t)o * 1152 + i) * 16 + k) * 8);
        float4 v0 = src[0], v1 = src[1];
        float vf[8] = {v0.x, v0.y, v0.z, v0.w, v1.x, v1.y, v1.z, v1.w};
        ushort8v hi;
        #pragma unroll
        for (int j = 0; j < 8; ++j) hi[j] = f2bf(vf[j]);
        *reinterpret_cast<ushort8v*>(Wp + (((size_t)i * 64 + o) * 16 + k) * 8) = hi;
    } else {
        int tid = (bid - 4608) * 256 + threadIdx.x;
        int b = tid & 63, i = tid >> 6;
        const float4* src = (const float4*)(x + ((size_t)b * 1152 + i) * 8);
        float4 v0 = src[0], v1 = src[1];
        float vf[8] = {v0.x, v0.y, v0.z, v0.w, v1.x, v1.y, v1.z, v1.w};
        ushort8v hi, lo;
        #pragma unroll
        for (int j = 0; j < 8; ++j) {
            unsigned short h = f2bf(vf[j]);
            hi[j] = h;
            lo[j] = f2bf(vf[j] - bf2f(h));
        }
        size_t base = ((size_t)i * 2) * 512 + (size_t)b * 8;
        *reinterpret_cast<ushort8v*>(xpp + base)       = hi;
        *reinterpret_cast<ushort8v*>(xpp + base + 512) = lo;
    }
}

template<int ROUTED>
__global__ __launch_bounds__(1024, 4)
void caps_mfma(const unsigned short* __restrict__ Wp,
               const unsigned short* __restrict__ xp,
               const float* __restrict__ Vfp,
               unsigned short* __restrict__ spart) {
    __shared__ unsigned short wlds[2][IPB * 8192];
    __shared__ float zbuf[2][IPB][256];
    const int t = threadIdx.x;
    const int wv = t >> 6, l = t & 63;
    const int btile = blockIdx.x >> 6, chunk = blockIdx.x & 63;
    const int g = l >> 4, b15 = l & 15;
    const int o0 = wv * 4;
    const int i0 = chunk * CTI;
    const bool act = (g < 2);
    uint2 vpk[4];
    if (ROUTED) {
        #pragma unroll
        for (int oo = 0; oo < 4; ++oo) {
            f32x4 Vf = *reinterpret_cast<const f32x4*>(
                Vfp + (((size_t)btile * 64 + o0 + oo) * 64 + l) * 4);
            vpk[oo].x = (unsigned)f2bf(Vf[0]) | ((unsigned)f2bf(Vf[1]) << 16);
            vpk[oo].y = (unsigned)f2bf(Vf[2]) | ((unsigned)f2bf(Vf[3]) << 16);
        }
    }
    f32x4 s[4];
    #pragma unroll
    for (int oo = 0; oo < 4; ++oo) s[oo] = (f32x4){0.f, 0.f, 0.f, 0.f};
    const short8v z8 = {0, 0, 0, 0, 0, 0, 0, 0};
    #define STAGE2(buf, ibase)                                                    \
    {                                                                             \
        const ushort8v* srcb = reinterpret_cast<const ushort8v*>(                 \
            Wp + (size_t)(ibase) * 8192);                                         \
        _Pragma("unroll")                                                         \
        for (int r = 0; r < 2; ++r)                                               \
            __builtin_amdgcn_global_load_lds(                                     \
                (gu32*)(srcb + (r * 1024 + wv * 64 + l)),                         \
                (lu32*)&wlds[buf][(size_t)(r * 1024 + wv * 64) * 8], 16, 0, 0);   \
    }
    #define LOADB(i) (*reinterpret_cast<const short8v*>(                          \
        xp + (((size_t)(i) * 2 + g) * 64 + btile * 16 + b15) * 8))
    STAGE2(0, i0);
    short8v Bf0 = z8, Bf1 = z8;
    if (act) { Bf0 = LOADB(i0); Bf1 = LOADB(i0 + 1); }
    __syncthreads();
    const int aoffbase = b15 * 8;
    int cur = 0;
    for (int st = 0; st < NSTEP; ++st) {
        short8v Bn0 = Bf0, Bn1 = Bf1;
        if (st + 1 < NSTEP) {
            STAGE2(cur ^ 1, i0 + (st + 1) * IPB);
            if (act) {
                Bn0 = LOADB(i0 + (st + 1) * IPB);
                Bn1 = LOADB(i0 + (st + 1) * IPB + 1);
            }
        }
        if (!ROUTED) {
            #pragma unroll
            for (int oo = 0; oo < 4; ++oo) {
                short8v Af0 = z8, Af1 = z8;
                if (act) {
                    const int ao = (o0 + oo) * 128 + aoffbase;
                    Af0 = *reinterpret_cast<const short8v*>(&wlds[cur][0] + ao);
                    Af1 = *reinterpret_cast<const short8v*>(&wlds[cur][8192] + ao);
                }
                s[oo] = __builtin_amdgcn_mfma_f32_16x16x32_bf16(Af0, Bf0, s[oo], 0, 0, 0);
                s[oo] = __builtin_amdgcn_mfma_f32_16x16x32_bf16(Af1, Bf1, s[oo], 0, 0, 0);
            }
            __syncthreads();
        } else {
            f32x4 u[IPB][4];
            float lg[IPB][4];
            float Zp0 = 0.f, Zp1 = 0.f;
            #pragma unroll
            for (int oo = 0; oo < 4; ++oo) {
                short8v Af0 = z8, Af1 = z8;
                if (act) {
                    const int ao = (o0 + oo) * 128 + aoffbase;
                    Af0 = *reinterpret_cast<const short8v*>(&wlds[cur][0] + ao);
                    Af1 = *reinterpret_cast<const short8v*>(&wlds[cur][8192] + ao);
                }
                f32x4 zz = {0.f, 0.f, 0.f, 0.f};
                u[0][oo] = __builtin_amdgcn_mfma_f32_16x16x32_bf16(Af0, Bf0, zz, 0, 0, 0);
                u[1][oo] = __builtin_amdgcn_mfma_f32_16x16x32_bf16(Af1, Bf1, zz, 0, 0, 0);
                float p0 = u[0][oo][0] * lo16f(vpk[oo].x);
                p0 = fmaf(u[0][oo][1], hi16f(vpk[oo].x), p0);
                p0 = fmaf(u[0][oo][2], lo16f(vpk[oo].y), p0);
                p0 = fmaf(u[0][oo][3], hi16f(vpk[oo].y), p0);
                float p1 = u[1][oo][0] * lo16f(vpk[oo].x);
                p1 = fmaf(u[1][oo][1], hi16f(vpk[oo].x), p1);
                p1 = fmaf(u[1][oo][2], lo16f(vpk[oo].y), p1);
                p1 = fmaf(u[1][oo][3], hi16f(vpk[oo].y), p1);
                p0 += __shfl_xor(p0, 16, 64);  p1 += __shfl_xor(p1, 16, 64);
                p0 += __shfl_xor(p0, 32, 64);  p1 += __shfl_xor(p1, 32, 64);
                float e0 = __expf(p0), e1 = __expf(p1);
                lg[0][oo] = e0; lg[1][oo] = e1;
                Zp0 += e0; Zp1 += e1;
            }
            if (l < 16) {
                zbuf[st & 1][0][wv * 16 + l] = Zp0;
                zbuf[st & 1][1][wv * 16 + l] = Zp1;
            }
            __syncthreads();
            float Z0 = zbuf[st & 1][0][b15];
            float Z1 = zbuf[st & 1][1][b15];
            #pragma unroll
            for (int w2 = 1; w2 < 16; ++w2) {
                Z0 += zbuf[st & 1][0][w2 * 16 + b15];
                Z1 += zbuf[st & 1][1][w2 * 16 + b15];
            }
            float rz0 = 1.0f / Z0, rz1 = 1.0f / Z1;
            #pragma unroll
            for (int oo = 0; oo < 4; ++oo) {
                float c0 = lg[0][oo] * rz0;
                float c1 = lg[1][oo] * rz1;
                s[oo][0] = fmaf(c0, u[0][oo][0], fmaf(c1, u[1][oo][0], s[oo][0]));
                s[oo][1] = fmaf(c0, u[0][oo][1], fmaf(c1, u[1][oo][1], s[oo][1]));
                s[oo][2] = fmaf(c0, u[0][oo][2], fmaf(c1, u[1][oo][2], s[oo][2]));
                s[oo][3] = fmaf(c0, u[0][oo][3], fmaf(c1, u[1][oo][3], s[oo][3]));
            }
        }
        Bf0 = Bn0; Bf1 = Bn1;
        cur ^= 1;
    }
    const float fin = ROUTED ? 1.0f : (1.0f / 64.0f);
    #pragma unroll
    for (int oo = 0; oo < 4; ++oo) {
        f32x4 vv = s[oo] * fin;
        uint2 pk;
        pk.x = (unsigned)f2bf(vv[0]) | ((unsigned)f2bf(vv[1]) << 16);
        pk.y = (unsigned)f2bf(vv[2]) | ((unsigned)f2bf(vv[3]) << 16);
        *reinterpret_cast<uint2*>(spart +
            ((((size_t)chunk * 4 + btile) * 64 + (o0 + oo)) * 64 + l) * 4) = pk;
    }
    #undef STAGE2
    #undef LOADB
}

template<int MODE>
__global__ __launch_bounds__(256)
void reduce2(const unsigned short* __restrict__ spart, float* __restrict__ Vfp,
             float* __restrict__ out) {
    __shared__ f32x4 red[256];
    const int t = threadIdx.x;
    const int l = t & 63, cq = t >> 6;
    const int pair = blockIdx.x;
    const int btile = pair >> 6, o = pair & 63;
    f32x4 acc = {0.f, 0.f, 0.f, 0.f};
    const unsigned short* base = spart + (((size_t)btile * 64 + o) * 64 + l) * 4;
    for (int c = cq * (CNCH/4); c < (cq + 1) * (CNCH/4); ++c) {
        uint2 w = *reinterpret_cast<const uint2*>(base + (size_t)c * 65536);
        acc[0] += lo16f(w.x); acc[1] += hi16f(w.x);
        acc[2] += lo16f(w.y); acc[3] += hi16f(w.y);
    }
    red[t] = acc;
    __syncthreads();
    if (cq == 0) {
        acc = red[l] + red[64 + l] + red[128 + l] + red[192 + l];
        float n2 = acc[0]*acc[0] + acc[1]*acc[1] + acc[2]*acc[2] + acc[3]*acc[3];
        n2 += __shfl_xor(n2, 16, 64);
        n2 += __shfl_xor(n2, 32, 64);
        const float scale = n2 / (1.0f + n2) / sqrtf(n2 + 1e-7f);
        f32x4 v = acc * scale;
        float* vp = Vfp + (((size_t)btile * 64 + o) * 64 + l) * 4;
        if (MODE == 0) {
            *reinterpret_cast<f32x4*>(vp) = v;
        } else if (MODE == 1) {
            f32x4 old = *reinterpret_cast<const f32x4*>(vp);
            *reinterpret_cast<f32x4*>(vp) = old + v;
        } else {
            const int b = btile * 16 + (l & 15), gq = l >> 4;
            *reinterpret_cast<f32x4*>(out + (((size_t)b * 64 + o) * 16 + gq * 4)) = v;
        }
    }
}

// ------------------------- round-5 fallback (small ws, proven) -------------------------
#define FTI 18
#define FNCH 64

__device__ __forceinline__ void load_lds16(const float4* gp, float4* lp) {
    __builtin_amdgcn_global_load_lds((gu32*)gp, (lu32*)lp, 16, 0, 0);
}
__device__ __forceinline__ float rfl(float v) {
    return __builtin_bit_cast(float, __builtin_amdgcn_readfirstlane(__builtin_bit_cast(int, v)));
}

template<bool UNIFORM>
__global__ __launch_bounds__(256, 2)
void caps_route_fb(const float* __restrict__ x, const float* __restrict__ W,
                   const float* __restrict__ Vsum, float* __restrict__ s_out) {
    __shared__ float4 wlds[2][2048];
    __shared__ float4 xlds[8 * FTI * 2];
    const int t = threadIdx.x;
    const int w = t >> 6, o = t & 63;
    const int chunk = blockIdx.x % FNCH, bblk = blockIdx.x / FNCH;
    const int i0 = chunk * FTI, bbase = bblk * 8 + w * 2;
    const float4* __restrict__ xg = (const float4*)x;
    const float4* __restrict__ Wg = (const float4*)W;
    for (int e = t; e < 8 * FTI * 2; e += 256) {
        int bb = e / (FTI * 2), r = e % (FTI * 2);
        xlds[e] = xg[((bblk * 8 + bb) * 1152 + i0 + (r >> 1)) * 2 + (r & 1)];
    }
    const float4* wsrc = Wg + (size_t)o * 36864 + (size_t)i0 * 32 + w * 8;
    #pragma unroll
    for (int r = 0; r < 8; ++r) load_lds16(wsrc + r, &wlds[0][(w * 8 + r) * 64]);
    float vsf[2][16];
    if (!UNIFORM) {
        const float4* vg = (const float4*)Vsum;
        #pragma unroll
        for (int ll = 0; ll < 2; ++ll)
            #pragma unroll
            for (int q = 0; q < 4; ++q) {
                float4 v = vg[((size_t)(bbase + ll) * 64 + o) * 4 + q];
                vsf[ll][q*4+0] = v.x; vsf[ll][q*4+1] = v.y;
                vsf[ll][q*4+2] = v.z; vsf[ll][q*4+3] = v.w;
            }
    }
    float sacc[2][16];
    #pragma unroll
    for (int ll = 0; ll < 2; ++ll)
        #pragma unroll
        for (int k = 0; k < 16; ++k) sacc[ll][k] = 0.0f;
    for (int ii = 0; ii < FTI; ++ii) {
        const int cur = ii & 1;
        __syncthreads();
        if (ii + 1 < FTI) {
            const float4* ws = wsrc + (size_t)(ii + 1) * 32;
            #pragma unroll
            for (int r = 0; r < 8; ++r) load_lds16(ws + r, &wlds[cur ^ 1][(w * 8 + r) * 64]);
        }
        float4 A0 = xlds[(w*2+0)*(FTI*2) + ii*2 + 0];
        float4 B0 = xlds[(w*2+0)*(FTI*2) + ii*2 + 1];
        float4 A1 = xlds[(w*2+1)*(FTI*2) + ii*2 + 0];
        float4 B1 = xlds[(w*2+1)*(FTI*2) + ii*2 + 1];
        float xa0x=rfl(A0.x),xa0y=rfl(A0.y),xa0z=rfl(A0.z),xa0w=rfl(A0.w);
        float xb0x=rfl(B0.x),xb0y=rfl(B0.y),xb0z=rfl(B0.z),xb0w=rfl(B0.w);
        float xa1x=rfl(A1.x),xa1y=rfl(A1.y),xa1z=rfl(A1.z),xa1w=rfl(A1.w);
        float xb1x=rfl(B1.x),xb1y=rfl(B1.y),xb1z=rfl(B1.z),xb1w=rfl(B1.w);
        const float4* wb = wlds[cur];
        float u[2][16];
        float logit0 = 0.0f, logit1 = 0.0f;
        #pragma unroll
        for (int k = 0; k < 16; ++k) {
            float4 w0 = wb[(2*k  )*64 + o];
            float4 w1 = wb[(2*k+1)*64 + o];
            float uk0 = w0.x*xa0x; uk0=fmaf(w0.y,xa0y,uk0); uk0=fmaf(w0.z,xa0z,uk0);
            uk0=fmaf(w0.w,xa0w,uk0); uk0=fmaf(w1.x,xb0x,uk0); uk0=fmaf(w1.y,xb0y,uk0);
            uk0=fmaf(w1.z,xb0z,uk0); uk0=fmaf(w1.w,xb0w,uk0);
            float uk1 = w0.x*xa1x; uk1=fmaf(w0.y,xa1y,uk1); uk1=fmaf(w0.z,xa1z,uk1);
            uk1=fmaf(w0.w,xa1w,uk1); uk1=fmaf(w1.x,xb1x,uk1); uk1=fmaf(w1.y,xb1y,uk1);
            uk1=fmaf(w1.z,xb1z,uk1); uk1=fmaf(w1.w,xb1w,uk1);
            u[0][k]=uk0; u[1][k]=uk1;
            if (!UNIFORM) { logit0=fmaf(vsf[0][k],uk0,logit0); logit1=fmaf(vsf[1][k],uk1,logit1); }
        }
        float c0, c1;
        if (UNIFORM) { c0 = c1 = 1.0f/64.0f; }
        else {
            float m0=logit0, m1=logit1;
            #pragma unroll
            for (int d=32; d>=1; d>>=1) { m0=fmaxf(m0,__shfl_xor(m0,d,64)); m1=fmaxf(m1,__shfl_xor(m1,d,64)); }
            float e0=__expf(logit0-m0), e1=__expf(logit1-m1);
            float s0=e0, s1=e1;
            #pragma unroll
            for (int d=32; d>=1; d>>=1) { s0+=__shfl_xor(s0,d,64); s1+=__shfl_xor(s1,d,64); }
            c0=e0/s0; c1=e1/s1;
        }
        #pragma unroll
        for (int k = 0; k < 16; ++k) {
            sacc[0][k]=fmaf(c0,u[0][k],sacc[0][k]);
            sacc[1][k]=fmaf(c1,u[1][k],sacc[1][k]);
        }
    }
    #pragma unroll
    for (int ll = 0; ll < 2; ++ll) {
        float4* sp = (float4*)s_out + (((size_t)chunk * 64 + (bbase + ll)) * 64 + o) * 4;
        sp[0]=make_float4(sacc[ll][0],sacc[ll][1],sacc[ll][2],sacc[ll][3]);
        sp[1]=make_float4(sacc[ll][4],sacc[ll][5],sacc[ll][6],sacc[ll][7]);
        sp[2]=make_float4(sacc[ll][8],sacc[ll][9],sacc[ll][10],sacc[ll][11]);
        sp[3]=make_float4(sacc[ll][12],sacc[ll][13],sacc[ll][14],sacc[ll][15]);
    }
}

template<int MODE>
__global__ __launch_bounds__(256)
void reduce_squash_fb(const float* __restrict__ sp, float* __restrict__ Vs, float* __restrict__ out) {
    const int t = threadIdx.x;
    const int p = t >> 4, q = t & 15;
    const int pair = blockIdx.x * 16 + p;
    const int b = pair >> 6, o = pair & 63;
    float acc[16];
    #pragma unroll
    for (int k = 0; k < 16; ++k) acc[k] = 0.0f;
    const float4* base = (const float4*)sp;
    for (int c = q * (FNCH/16); c < (q + 1) * (FNCH/16); ++c) {
        const float4* pptr = base + (((size_t)c * 64 + b) * 64 + o) * 4;
        float4 v0=pptr[0],v1=pptr[1],v2=pptr[2],v3=pptr[3];
        acc[0]+=v0.x;acc[1]+=v0.y;acc[2]+=v0.z;acc[3]+=v0.w;
        acc[4]+=v1.x;acc[5]+=v1.y;acc[6]+=v1.z;acc[7]+=v1.w;
        acc[8]+=v2.x;acc[9]+=v2.y;acc[10]+=v2.z;acc[11]+=v2.w;
        acc[12]+=v3.x;acc[13]+=v3.y;acc[14]+=v3.z;acc[15]+=v3.w;
    }
    #pragma unroll
    for (int d = 1; d < 16; d <<= 1)
        #pragma unroll
        for (int k = 0; k < 16; ++k) acc[k] += __shfl_xor(acc[k], d, 64);
    if (q == 0) {
        float n2 = 0.0f;
        #pragma unroll
        for (int k = 0; k < 16; ++k) n2 = fmaf(acc[k], acc[k], n2);
        const float scale = n2 / (1.0f + n2) / sqrtf(n2 + 1e-7f);
        if (MODE == 0) {
            float4* vf = (float4*)Vs + (size_t)pair * 4;
            #pragma unroll
            for (int r = 0; r < 4; ++r)
                vf[r] = make_float4(scale*acc[r*4+0],scale*acc[r*4+1],scale*acc[r*4+2],scale*acc[r*4+3]);
        } else if (MODE == 1) {
            float4* vf = (float4*)Vs + (size_t)pair * 4;
            #pragma unroll
            for (int r = 0; r < 4; ++r) {
                float4 v = vf[r];
                v.x=fmaf(scale,acc[r*4+0],v.x); v.y=fmaf(scale,acc[r*4+1],v.y);
                v.z=fmaf(scale,acc[r*4+2],v.z); v.w=fmaf(scale,acc[r*4+3],v.w);
                vf[r] = v;
            }
        } else {
            float4* of = (float4*)out + (size_t)pair * 4;
            #pragma unroll
            for (int r = 0; r < 4; ++r)
                of[r] = make_float4(scale*acc[r*4+0],scale*acc[r*4+1],scale*acc[r*4+2],scale*acc[r*4+3]);
        }
    }
}
// -----------------------------------------------------------------------------

extern "C" void kernel_launch(void* const* d_in, const int* in_sizes, int n_in,
                              void* d_out, int out_size, void* d_ws, size_t ws_size,
                              hipStream_t stream) {
    const float* x = (const float*)d_in[0];   // [64,1152,8]
    const float* W = (const float*)d_in[1];   // [64,1152,16,8]
    float* out = (float*)d_out;               // [64,64,16]

    float* Vfp = (float*)d_ws;                                       // 65536 f32
    unsigned short* spart = (unsigned short*)(Vfp + 65536);          // CNCH*65536 bf16
    unsigned short* Wp = spart + (size_t)CNCH * 65536;               // hi-only
    unsigned short* xpp = Wp + (size_t)1152 * 64 * 128;
    const size_t need_full = (size_t)65536 * 4
        + ((size_t)CNCH * 65536 + (size_t)1152 * 64 * 128 + (size_t)1152 * 2 * 512) * 2;

    if (ws_size >= need_full) {
        void* kargs[] = {(void*)&W, (void*)&x, (void*)&Wp, (void*)&xpp,
                         (void*)&Vfp, (void*)&spart, (void*)&out};
        hipError_t err = hipLaunchCooperativeKernel((const void*)caps_fused,
                                                    dim3(256), dim3(1024),
                                                    kargs, 0, stream);
        if (err != hipSuccess) {
            // round-15 multi-dispatch fallback (proven, 88.2 us)
            xform<<<4608 + 288, 256, 0, stream>>>(W, x, Wp, xpp);
            caps_mfma<0><<<256, 1024, 0, stream>>>(Wp, xpp, Vfp, spart);
            reduce2<0><<<256, 256, 0, stream>>>(spart, Vfp, out);
            caps_mfma<1><<<256, 1024, 0, stream>>>(Wp, xpp, Vfp, spart);
            reduce2<1><<<256, 256, 0, stream>>>(spart, Vfp, out);
            caps_mfma<1><<<256, 1024, 0, stream>>>(Wp, xpp, Vfp, spart);
            reduce2<2><<<256, 256, 0, stream>>>(spart, Vfp, out);
        }
    } else {
        // proven round-5 path (needs ~17 MB)
        float* Vs = (float*)d_ws;
        float* sp = Vs + 65536;
        dim3 grid(8 * FNCH), blk(256);
        dim3 rg(256), rb(256);
        caps_route_fb<true ><<<grid, blk, 0, stream>>>(x, W, nullptr, sp);
        reduce_squash_fb<0><<<rg, rb, 0, stream>>>(sp, Vs, out);
        caps_route_fb<false><<<grid, blk, 0, stream>>>(x, W, Vs, sp);
        reduce_squash_fb<1><<<rg, rb, 0, stream>>>(sp, Vs, out);
        caps_route_fb<false><<<grid, blk, 0, stream>>>(x, W, Vs, sp);
        reduce_squash_fb<2><<<rg, rb, 0, stream>>>(sp, Vs, out);
    }
}

// Round 17
// 127.457 us; speedup vs baseline: 2.2592x; 2.2592x over previous
//
#include <hip/hip_runtime.h>
#include <math.h>

// B=64, N_in=1152, K_in=8, N_out=64, K_out=16, ITER=3
// MFMA path, W bf16-HI only. 512-thread blocks (8 waves, 8 o/wave),
// __launch_bounds__(512,2): 1024-thr kernels are hard-capped at 64 VGPRs by
// the compiler (r12/r13/r16 evidence) and spill the ~110-reg routed live set;
// 256/512-thr with min-waves=2 allocate 112-128 (r4/r5). CTI=9, CNCH=128 ->
// 512 blocks = 2 blocks/CU for cross-block TLP over barrier stalls.

#define CTI 9         // i per chunk
#define NSTEP 9       // one i-slice per step
#define CNCH 128      // 1152 / CTI

typedef __attribute__((ext_vector_type(8))) short short8v;
typedef __attribute__((ext_vector_type(8))) unsigned short ushort8v;
typedef __attribute__((ext_vector_type(4))) float f32x4;

typedef const __attribute__((address_space(1))) unsigned int gu32;
typedef __attribute__((address_space(3))) unsigned int lu32;

__device__ __forceinline__ unsigned short f2bf(float f) {   // RTNE
    unsigned u = __builtin_bit_cast(unsigned, f);
    u = u + 0x7FFFu + ((u >> 16) & 1u);
    return (unsigned short)(u >> 16);
}
__device__ __forceinline__ float bf2f(unsigned short h) {
    unsigned u = ((unsigned)h) << 16;
    return __builtin_bit_cast(float, u);
}
__device__ __forceinline__ float lo16f(unsigned u) {
    return __builtin_bit_cast(float, u << 16);
}
__device__ __forceinline__ float hi16f(unsigned u) {
    return __builtin_bit_cast(float, u & 0xFFFF0000u);
}

// W[o][i][k][j] f32 -> Wp[i][o][k][j] bf16 (HI only); x -> xp[i][p][b][j] hi/lo
__global__ __launch_bounds__(256)
void xform(const float* __restrict__ W, const float* __restrict__ x,
           unsigned short* __restrict__ Wp, unsigned short* __restrict__ xpp) {
    const int bid = blockIdx.x;
    if (bid < 4608) {
        int tid = bid * 256 + threadIdx.x;          // 1152*64*16
        int k = tid & 15, o = (tid >> 4) & 63, i = tid >> 10;
        const float4* src = (const float4*)(W + (((size_t)o * 1152 + i) * 16 + k) * 8);
        float4 v0 = src[0], v1 = src[1];
        float vf[8] = {v0.x, v0.y, v0.z, v0.w, v1.x, v1.y, v1.z, v1.w};
        ushort8v hi;
        #pragma unroll
        for (int j = 0; j < 8; ++j) hi[j] = f2bf(vf[j]);
        *reinterpret_cast<ushort8v*>(Wp + (((size_t)i * 64 + o) * 16 + k) * 8) = hi;
    } else {
        int tid = (bid - 4608) * 256 + threadIdx.x; // 1152*64
        int b = tid & 63, i = tid >> 6;
        const float4* src = (const float4*)(x + ((size_t)b * 1152 + i) * 8);
        float4 v0 = src[0], v1 = src[1];
        float vf[8] = {v0.x, v0.y, v0.z, v0.w, v1.x, v1.y, v1.z, v1.w};
        ushort8v hi, lo;
        #pragma unroll
        for (int j = 0; j < 8; ++j) {
            unsigned short h = f2bf(vf[j]);
            hi[j] = h;
            lo[j] = f2bf(vf[j] - bf2f(h));
        }
        size_t base = ((size_t)i * 2) * 512 + (size_t)b * 8;
        *reinterpret_cast<ushort8v*>(xpp + base)       = hi;
        *reinterpret_cast<ushort8v*>(xpp + base + 512) = lo;
    }
}

// Routing pass. Grid 512 = btile(4) x chunk(128); btile-sharers differ by 128
// in blockIdx -> same XCD. Block: 512 thr = 8 waves; wave wv owns o = wv*8..+7.
// Lanes: col b = l&15 (= A-row k), group g = l>>4.
// K-slots: 0-7 Whi*xhi, 8-15 Whi*xlo, 16-31 zero (A=B=0 for g>=2).
// Wp staged 1 i-slice (16 KB) per step, double-buffered; ONE barrier/step.
template<int ROUTED>
__global__ __launch_bounds__(512, 2)
void caps_mfma(const unsigned short* __restrict__ Wp,
               const unsigned short* __restrict__ xp,
               const float* __restrict__ Vfp,
               unsigned short* __restrict__ spart) {
    __shared__ unsigned short wlds[2][8192];   // 2 x 16 KB (hi only)
    __shared__ float zbuf[2][128];             // [step parity][wave*16+b15]

    const int t = threadIdx.x;
    const int wv = t >> 6, l = t & 63;
    const int btile = blockIdx.x >> 7, chunk = blockIdx.x & 127;
    const int g = l >> 4, b15 = l & 15;
    const int o0 = wv * 8;
    const int i0 = chunk * CTI;
    const bool act = (g < 2);
    const short8v z8 = {0, 0, 0, 0, 0, 0, 0, 0};

    // Vsum packed to bf16 pairs: 16 VGPRs
    uint2 vpk[8];
    if (ROUTED) {
        #pragma unroll
        for (int oo = 0; oo < 8; ++oo) {
            f32x4 Vf = *reinterpret_cast<const f32x4*>(
                Vfp + (((size_t)btile * 64 + o0 + oo) * 64 + l) * 4);
            vpk[oo].x = (unsigned)f2bf(Vf[0]) | ((unsigned)f2bf(Vf[1]) << 16);
            vpk[oo].y = (unsigned)f2bf(Vf[2]) | ((unsigned)f2bf(Vf[3]) << 16);
        }
    }

    f32x4 s[8];
    #pragma unroll
    for (int oo = 0; oo < 8; ++oo) s[oo] = (f32x4){0.f, 0.f, 0.f, 0.f};

    // DMA one 16 KB slice: 2 rounds x 8 waves x 64 lanes x 16 B
    #define STAGE(buf, i)                                                         \
    {                                                                             \
        const ushort8v* srcb = reinterpret_cast<const ushort8v*>(                 \
            Wp + (size_t)(i) * 8192);                                             \
        _Pragma("unroll")                                                         \
        for (int r = 0; r < 2; ++r)                                               \
            __builtin_amdgcn_global_load_lds(                                     \
                (gu32*)(srcb + (r * 512 + wv * 64 + l)),                          \
                (lu32*)&wlds[buf][(size_t)(r * 512 + wv * 64) * 8], 16, 0, 0);    \
    }

    // B-frag: plane = g (0=hi, 1=lo); zero for g>=2
    #define LOADB(i) (*reinterpret_cast<const short8v*>(                          \
        xp + (((size_t)(i) * 2 + g) * 64 + btile * 16 + b15) * 8))

    STAGE(0, i0);
    short8v Bf = z8;
    if (act) Bf = LOADB(i0);
    __syncthreads();   // prologue DMA complete

    const int aoffbase = b15 * 8;

    int cur = 0;
    for (int st = 0; st < NSTEP; ++st) {
        short8v Bn = Bf;
        if (st + 1 < NSTEP) {
            STAGE(cur ^ 1, i0 + st + 1);
            if (act) Bn = LOADB(i0 + st + 1);
        }

        if (!ROUTED) {
            #pragma unroll
            for (int oo = 0; oo < 8; ++oo) {
                short8v Af = z8;
                if (act)
                    Af = *reinterpret_cast<const short8v*>(
                        &wlds[cur][0] + ((o0 + oo) * 128 + aoffbase));
                s[oo] = __builtin_amdgcn_mfma_f32_16x16x32_bf16(Af, Bf, s[oo], 0, 0, 0);
            }
            __syncthreads();   // DMA(next) complete + buffer-reuse safety
        } else {
            f32x4 u[8];
            float lg[8];
            float Zp = 0.f;
            #pragma unroll
            for (int oo = 0; oo < 8; ++oo) {
                short8v Af = z8;
                if (act)
                    Af = *reinterpret_cast<const short8v*>(
                        &wlds[cur][0] + ((o0 + oo) * 128 + aoffbase));
                f32x4 zz = {0.f, 0.f, 0.f, 0.f};
                u[oo] = __builtin_amdgcn_mfma_f32_16x16x32_bf16(Af, Bf, zz, 0, 0, 0);
                float p = u[oo][0] * lo16f(vpk[oo].x);
                p = fmaf(u[oo][1], hi16f(vpk[oo].x), p);
                p = fmaf(u[oo][2], lo16f(vpk[oo].y), p);
                p = fmaf(u[oo][3], hi16f(vpk[oo].y), p);
                p += __shfl_xor(p, 16, 64);    // sum over k-groups
                p += __shfl_xor(p, 32, 64);
                // logits bounded (|logit| <= ~1.2): exp without max-subtraction
                float e = __expf(p);
                lg[oo] = e;
                Zp += e;
            }
            if (l < 16) zbuf[st & 1][wv * 16 + l] = Zp;
            __syncthreads();                   // Z visible; DMA(next) drained
            float Z = zbuf[st & 1][b15];
            #pragma unroll
            for (int w2 = 1; w2 < 8; ++w2) Z += zbuf[st & 1][w2 * 16 + b15];
            float rz = 1.0f / Z;
            #pragma unroll
            for (int oo = 0; oo < 8; ++oo) {
                float c = lg[oo] * rz;
                s[oo][0] = fmaf(c, u[oo][0], s[oo][0]);
                s[oo][1] = fmaf(c, u[oo][1], s[oo][1]);
                s[oo][2] = fmaf(c, u[oo][2], s[oo][2]);
                s[oo][3] = fmaf(c, u[oo][3], s[oo][3]);
            }
        }
        Bf = Bn;
        cur ^= 1;
    }

    // bf16 partials: [chunk][btile][o][l][4k], 8 B/lane coalesced
    const float fin = ROUTED ? 1.0f : (1.0f / 64.0f);
    #pragma unroll
    for (int oo = 0; oo < 8; ++oo) {
        f32x4 vv = s[oo] * fin;
        uint2 pk;
        pk.x = (unsigned)f2bf(vv[0]) | ((unsigned)f2bf(vv[1]) << 16);
        pk.y = (unsigned)f2bf(vv[2]) | ((unsigned)f2bf(vv[3]) << 16);
        *reinterpret_cast<uint2*>(spart +
            ((((size_t)chunk * 4 + btile) * 64 + (o0 + oo)) * 64 + l) * 4) = pk;
    }
    #undef STAGE
    #undef LOADB
}

// Sum CNCH bf16 chunk-partials, squash, update Vfp / write out.
// Grid 256 blocks (one (btile,o) pair) x 256 thr: l = t&63, cq = t>>6.
template<int MODE>
__global__ __launch_bounds__(256)
void reduce2(const unsigned short* __restrict__ spart, float* __restrict__ Vfp,
             float* __restrict__ out) {
    __shared__ f32x4 red[256];
    const int t = threadIdx.x;
    const int l = t & 63, cq = t >> 6;
    const int pair = blockIdx.x;               // btile*64 + o
    const int btile = pair >> 6, o = pair & 63;

    f32x4 acc = {0.f, 0.f, 0.f, 0.f};
    const unsigned short* base = spart + (((size_t)btile * 64 + o) * 64 + l) * 4;
    for (int c = cq * (CNCH/4); c < (cq + 1) * (CNCH/4); ++c) {
        uint2 w = *reinterpret_cast<const uint2*>(base + (size_t)c * 65536);
        acc[0] += lo16f(w.x); acc[1] += hi16f(w.x);
        acc[2] += lo16f(w.y); acc[3] += hi16f(w.y);
    }
    red[t] = acc;
    __syncthreads();
    if (cq == 0) {
        acc = red[l] + red[64 + l] + red[128 + l] + red[192 + l];
        float n2 = acc[0]*acc[0] + acc[1]*acc[1] + acc[2]*acc[2] + acc[3]*acc[3];
        n2 += __shfl_xor(n2, 16, 64);
        n2 += __shfl_xor(n2, 32, 64);
        const float scale = n2 / (1.0f + n2) / sqrtf(n2 + 1e-7f);
        f32x4 v = acc * scale;
        float* vp = Vfp + (((size_t)btile * 64 + o) * 64 + l) * 4;
        if (MODE == 0) {
            *reinterpret_cast<f32x4*>(vp) = v;
        } else if (MODE == 1) {
            f32x4 old = *reinterpret_cast<const f32x4*>(vp);
            *reinterpret_cast<f32x4*>(vp) = old + v;
        } else {
            const int b = btile * 16 + (l & 15), gq = l >> 4;
            *reinterpret_cast<f32x4*>(out + (((size_t)b * 64 + o) * 16 + gq * 4)) = v;
        }
    }
}

// ------------------------- round-5 fallback (small ws, proven) -------------------------
#define FTI 18
#define FNCH 64

__device__ __forceinline__ void load_lds16(const float4* gp, float4* lp) {
    __builtin_amdgcn_global_load_lds((gu32*)gp, (lu32*)lp, 16, 0, 0);
}
__device__ __forceinline__ float rfl(float v) {
    return __builtin_bit_cast(float, __builtin_amdgcn_readfirstlane(__builtin_bit_cast(int, v)));
}

template<bool UNIFORM>
__global__ __launch_bounds__(256, 2)
void caps_route_fb(const float* __restrict__ x, const float* __restrict__ W,
                   const float* __restrict__ Vsum, float* __restrict__ s_out) {
    __shared__ float4 wlds[2][2048];
    __shared__ float4 xlds[8 * FTI * 2];
    const int t = threadIdx.x;
    const int w = t >> 6, o = t & 63;
    const int chunk = blockIdx.x % FNCH, bblk = blockIdx.x / FNCH;
    const int i0 = chunk * FTI, bbase = bblk * 8 + w * 2;
    const float4* __restrict__ xg = (const float4*)x;
    const float4* __restrict__ Wg = (const float4*)W;
    for (int e = t; e < 8 * FTI * 2; e += 256) {
        int bb = e / (FTI * 2), r = e % (FTI * 2);
        xlds[e] = xg[((bblk * 8 + bb) * 1152 + i0 + (r >> 1)) * 2 + (r & 1)];
    }
    const float4* wsrc = Wg + (size_t)o * 36864 + (size_t)i0 * 32 + w * 8;
    #pragma unroll
    for (int r = 0; r < 8; ++r) load_lds16(wsrc + r, &wlds[0][(w * 8 + r) * 64]);
    float vsf[2][16];
    if (!UNIFORM) {
        const float4* vg = (const float4*)Vsum;
        #pragma unroll
        for (int ll = 0; ll < 2; ++ll)
            #pragma unroll
            for (int q = 0; q < 4; ++q) {
                float4 v = vg[((size_t)(bbase + ll) * 64 + o) * 4 + q];
                vsf[ll][q*4+0] = v.x; vsf[ll][q*4+1] = v.y;
                vsf[ll][q*4+2] = v.z; vsf[ll][q*4+3] = v.w;
            }
    }
    float sacc[2][16];
    #pragma unroll
    for (int ll = 0; ll < 2; ++ll)
        #pragma unroll
        for (int k = 0; k < 16; ++k) sacc[ll][k] = 0.0f;
    for (int ii = 0; ii < FTI; ++ii) {
        const int cur = ii & 1;
        __syncthreads();
        if (ii + 1 < FTI) {
            const float4* ws = wsrc + (size_t)(ii + 1) * 32;
            #pragma unroll
            for (int r = 0; r < 8; ++r) load_lds16(ws + r, &wlds[cur ^ 1][(w * 8 + r) * 64]);
        }
        float4 A0 = xlds[(w*2+0)*(FTI*2) + ii*2 + 0];
        float4 B0 = xlds[(w*2+0)*(FTI*2) + ii*2 + 1];
        float4 A1 = xlds[(w*2+1)*(FTI*2) + ii*2 + 0];
        float4 B1 = xlds[(w*2+1)*(FTI*2) + ii*2 + 1];
        float xa0x=rfl(A0.x),xa0y=rfl(A0.y),xa0z=rfl(A0.z),xa0w=rfl(A0.w);
        float xb0x=rfl(B0.x),xb0y=rfl(B0.y),xb0z=rfl(B0.z),xb0w=rfl(B0.w);
        float xa1x=rfl(A1.x),xa1y=rfl(A1.y),xa1z=rfl(A1.z),xa1w=rfl(A1.w);
        float xb1x=rfl(B1.x),xb1y=rfl(B1.y),xb1z=rfl(B1.z),xb1w=rfl(B1.w);
        const float4* wb = wlds[cur];
        float u[2][16];
        float logit0 = 0.0f, logit1 = 0.0f;
        #pragma unroll
        for (int k = 0; k < 16; ++k) {
            float4 w0 = wb[(2*k  )*64 + o];
            float4 w1 = wb[(2*k+1)*64 + o];
            float uk0 = w0.x*xa0x; uk0=fmaf(w0.y,xa0y,uk0); uk0=fmaf(w0.z,xa0z,uk0);
            uk0=fmaf(w0.w,xa0w,uk0); uk0=fmaf(w1.x,xb0x,uk0); uk0=fmaf(w1.y,xb0y,uk0);
            uk0=fmaf(w1.z,xb0z,uk0); uk0=fmaf(w1.w,xb0w,uk0);
            float uk1 = w0.x*xa1x; uk1=fmaf(w0.y,xa1y,uk1); uk1=fmaf(w0.z,xa1z,uk1);
            uk1=fmaf(w0.w,xa1w,uk1); uk1=fmaf(w1.x,xb1x,uk1); uk1=fmaf(w1.y,xb1y,uk1);
            uk1=fmaf(w1.z,xb1z,uk1); uk1=fmaf(w1.w,xb1w,uk1);
            u[0][k]=uk0; u[1][k]=uk1;
            if (!UNIFORM) { logit0=fmaf(vsf[0][k],uk0,logit0); logit1=fmaf(vsf[1][k],uk1,logit1); }
        }
        float c0, c1;
        if (UNIFORM) { c0 = c1 = 1.0f/64.0f; }
        else {
            float m0=logit0, m1=logit1;
            #pragma unroll
            for (int d=32; d>=1; d>>=1) { m0=fmaxf(m0,__shfl_xor(m0,d,64)); m1=fmaxf(m1,__shfl_xor(m1,d,64)); }
            float e0=__expf(logit0-m0), e1=__expf(logit1-m1);
            float s0=e0, s1=e1;
            #pragma unroll
            for (int d=32; d>=1; d>>=1) { s0+=__shfl_xor(s0,d,64); s1+=__shfl_xor(s1,d,64); }
            c0=e0/s0; c1=e1/s1;
        }
        #pragma unroll
        for (int k = 0; k < 16; ++k) {
            sacc[0][k]=fmaf(c0,u[0][k],sacc[0][k]);
            sacc[1][k]=fmaf(c1,u[1][k],sacc[1][k]);
        }
    }
    #pragma unroll
    for (int ll = 0; ll < 2; ++ll) {
        float4* sp = (float4*)s_out + (((size_t)chunk * 64 + (bbase + ll)) * 64 + o) * 4;
        sp[0]=make_float4(sacc[ll][0],sacc[ll][1],sacc[ll][2],sacc[ll][3]);
        sp[1]=make_float4(sacc[ll][4],sacc[ll][5],sacc[ll][6],sacc[ll][7]);
        sp[2]=make_float4(sacc[ll][8],sacc[ll][9],sacc[ll][10],sacc[ll][11]);
        sp[3]=make_float4(sacc[ll][12],sacc[ll][13],sacc[ll][14],sacc[ll][15]);
    }
}

template<int MODE>
__global__ __launch_bounds__(256)
void reduce_squash_fb(const float* __restrict__ sp, float* __restrict__ Vs, float* __restrict__ out) {
    const int t = threadIdx.x;
    const int p = t >> 4, q = t & 15;
    const int pair = blockIdx.x * 16 + p;
    const int b = pair >> 6, o = pair & 63;
    float acc[16];
    #pragma unroll
    for (int k = 0; k < 16; ++k) acc[k] = 0.0f;
    const float4* base = (const float4*)sp;
    for (int c = q * (FNCH/16); c < (q + 1) * (FNCH/16); ++c) {
        const float4* pptr = base + (((size_t)c * 64 + b) * 64 + o) * 4;
        float4 v0=pptr[0],v1=pptr[1],v2=pptr[2],v3=pptr[3];
        acc[0]+=v0.x;acc[1]+=v0.y;acc[2]+=v0.z;acc[3]+=v0.w;
        acc[4]+=v1.x;acc[5]+=v1.y;acc[6]+=v1.z;acc[7]+=v1.w;
        acc[8]+=v2.x;acc[9]+=v2.y;acc[10]+=v2.z;acc[11]+=v2.w;
        acc[12]+=v3.x;acc[13]+=v3.y;acc[14]+=v3.z;acc[15]+=v3.w;
    }
    #pragma unroll
    for (int d = 1; d < 16; d <<= 1)
        #pragma unroll
        for (int k = 0; k < 16; ++k) acc[k] += __shfl_xor(acc[k], d, 64);
    if (q == 0) {
        float n2 = 0.0f;
        #pragma unroll
        for (int k = 0; k < 16; ++k) n2 = fmaf(acc[k], acc[k], n2);
        const float scale = n2 / (1.0f + n2) / sqrtf(n2 + 1e-7f);
        if (MODE == 0) {
            float4* vf = (float4*)Vs + (size_t)pair * 4;
            #pragma unroll
            for (int r = 0; r < 4; ++r)
                vf[r] = make_float4(scale*acc[r*4+0],scale*acc[r*4+1],scale*acc[r*4+2],scale*acc[r*4+3]);
        } else if (MODE == 1) {
            float4* vf = (float4*)Vs + (size_t)pair * 4;
            #pragma unroll
            for (int r = 0; r < 4; ++r) {
                float4 v = vf[r];
                v.x=fmaf(scale,acc[r*4+0],v.x); v.y=fmaf(scale,acc[r*4+1],v.y);
                v.z=fmaf(scale,acc[r*4+2],v.z); v.w=fmaf(scale,acc[r*4+3],v.w);
                vf[r] = v;
            }
        } else {
            float4* of = (float4*)out + (size_t)pair * 4;
            #pragma unroll
            for (int r = 0; r < 4; ++r)
                of[r] = make_float4(scale*acc[r*4+0],scale*acc[r*4+1],scale*acc[r*4+2],scale*acc[r*4+3]);
        }
    }
}
// -----------------------------------------------------------------------------

extern "C" void kernel_launch(void* const* d_in, const int* in_sizes, int n_in,
                              void* d_out, int out_size, void* d_ws, size_t ws_size,
                              hipStream_t stream) {
    const float* x = (const float*)d_in[0];   // [64,1152,8]
    const float* W = (const float*)d_in[1];   // [64,1152,16,8]
    float* out = (float*)d_out;               // [64,64,16]

    float* Vfp = (float*)d_ws;                                       // 65536 f32
    unsigned short* spart = (unsigned short*)(Vfp + 65536);          // CNCH*65536 bf16
    unsigned short* Wp = spart + (size_t)CNCH * 65536;               // hi-only
    unsigned short* xpp = Wp + (size_t)1152 * 64 * 128;
    const size_t need_full = (size_t)65536 * 4
        + ((size_t)CNCH * 65536 + (size_t)1152 * 64 * 128 + (size_t)1152 * 2 * 512) * 2;

    if (ws_size >= need_full) {
        xform<<<4608 + 288, 256, 0, stream>>>(W, x, Wp, xpp);
        caps_mfma<0><<<512, 512, 0, stream>>>(Wp, xpp, Vfp, spart);
        reduce2<0><<<256, 256, 0, stream>>>(spart, Vfp, out);
        caps_mfma<1><<<512, 512, 0, stream>>>(Wp, xpp, Vfp, spart);
        reduce2<1><<<256, 256, 0, stream>>>(spart, Vfp, out);
        caps_mfma<1><<<512, 512, 0, stream>>>(Wp, xpp, Vfp, spart);
        reduce2<2><<<256, 256, 0, stream>>>(spart, Vfp, out);
    } else {
        // proven round-5 path (needs ~17 MB)
        float* Vs = (float*)d_ws;
        float* sp = Vs + 65536;
        dim3 grid(8 * FNCH), blk(256);
        dim3 rg(256), rb(256);
        caps_route_fb<true ><<<grid, blk, 0, stream>>>(x, W, nullptr, sp);
        reduce_squash_fb<0><<<rg, rb, 0, stream>>>(sp, Vs, out);
        caps_route_fb<false><<<grid, blk, 0, stream>>>(x, W, Vs, sp);
        reduce_squash_fb<1><<<rg, rb, 0, stream>>>(sp, Vs, out);
        caps_route_fb<false><<<grid, blk, 0, stream>>>(x, W, Vs, sp);
        reduce_squash_fb<2><<<rg, rb, 0, stream>>>(sp, Vs, out);
    }
}

// Round 18
// 102.930 us; speedup vs baseline: 2.7976x; 1.2383x over previous
//
#include <hip/hip_runtime.h>
#include <math.h>

// B=64, N_in=1152, K_in=8, N_out=64, K_out=16, ITER=3
// r15 structure (best: 88.2us) + spill fix: 1024-thr kernels are hard-capped
// at 64 VGPRs (r12/r13/r16 evidence); r15's u[2][4] (32 regs) crossing the
// Z-barrier spilled. Fix: recompute u post-barrier (8 extra cheap MFMAs/step),
// so only lg[8]+Bf[8] cross -> live ~55 <= 64, no spill. Post-barrier LDS
// reads race with next DMA under dbuf -> TRIPLE-buffer the 32KB stage unit
// (96KB LDS; 256 blocks = 1 block/CU anyway).

#define CTI 18        // i per chunk
#define IPB 2         // i per buffer step
#define NSTEP 9       // CTI / IPB
#define CNCH 64       // 1152 / CTI

typedef __attribute__((ext_vector_type(8))) short short8v;
typedef __attribute__((ext_vector_type(8))) unsigned short ushort8v;
typedef __attribute__((ext_vector_type(4))) float f32x4;

typedef const __attribute__((address_space(1))) unsigned int gu32;
typedef __attribute__((address_space(3))) unsigned int lu32;

__device__ __forceinline__ unsigned short f2bf(float f) {   // RTNE
    unsigned u = __builtin_bit_cast(unsigned, f);
    u = u + 0x7FFFu + ((u >> 16) & 1u);
    return (unsigned short)(u >> 16);
}
__device__ __forceinline__ float bf2f(unsigned short h) {
    unsigned u = ((unsigned)h) << 16;
    return __builtin_bit_cast(float, u);
}
__device__ __forceinline__ float lo16f(unsigned u) {
    return __builtin_bit_cast(float, u << 16);
}
__device__ __forceinline__ float hi16f(unsigned u) {
    return __builtin_bit_cast(float, u & 0xFFFF0000u);
}

// W[o][i][k][j] f32 -> Wp[i][o][k][j] bf16 (HI only); x -> xp[i][p][b][j] hi/lo
__global__ __launch_bounds__(256)
void xform(const float* __restrict__ W, const float* __restrict__ x,
           unsigned short* __restrict__ Wp, unsigned short* __restrict__ xpp) {
    const int bid = blockIdx.x;
    if (bid < 4608) {
        int tid = bid * 256 + threadIdx.x;          // 1152*64*16
        int k = tid & 15, o = (tid >> 4) & 63, i = tid >> 10;
        const float4* src = (const float4*)(W + (((size_t)o * 1152 + i) * 16 + k) * 8);
        float4 v0 = src[0], v1 = src[1];
        float vf[8] = {v0.x, v0.y, v0.z, v0.w, v1.x, v1.y, v1.z, v1.w};
        ushort8v hi;
        #pragma unroll
        for (int j = 0; j < 8; ++j) hi[j] = f2bf(vf[j]);
        *reinterpret_cast<ushort8v*>(Wp + (((size_t)i * 64 + o) * 16 + k) * 8) = hi;
    } else {
        int tid = (bid - 4608) * 256 + threadIdx.x; // 1152*64
        int b = tid & 63, i = tid >> 6;
        const float4* src = (const float4*)(x + ((size_t)b * 1152 + i) * 8);
        float4 v0 = src[0], v1 = src[1];
        float vf[8] = {v0.x, v0.y, v0.z, v0.w, v1.x, v1.y, v1.z, v1.w};
        ushort8v hi, lo;
        #pragma unroll
        for (int j = 0; j < 8; ++j) {
            unsigned short h = f2bf(vf[j]);
            hi[j] = h;
            lo[j] = f2bf(vf[j] - bf2f(h));
        }
        size_t base = ((size_t)i * 2) * 512 + (size_t)b * 8;
        *reinterpret_cast<ushort8v*>(xpp + base)       = hi;
        *reinterpret_cast<ushort8v*>(xpp + base + 512) = lo;
    }
}

// Routing pass. Grid 256 = btile(4) x chunk(64). Block: 1024 thr = 16 waves;
// wave wv owns o = wv*4..+4; lanes: col b = l&15 (= A-row k), group g = l>>4.
// K-slots: 0-7 Whi*xhi, 8-15 Whi*xlo, 16-31 zero. Triple-buffered 32KB stage.
template<int ROUTED>
__global__ __launch_bounds__(1024, 4)
void caps_mfma(const unsigned short* __restrict__ Wp,
               const unsigned short* __restrict__ xp,
               const float* __restrict__ Vfp,
               unsigned short* __restrict__ spart) {
    __shared__ unsigned short wlds[3][IPB * 8192];    // 3 x 32 KB (hi only)
    __shared__ float zbuf[2][IPB][256];               // [parity][sub-i][wave*16+b15]

    const int t = threadIdx.x;
    const int wv = t >> 6, l = t & 63;
    const int btile = blockIdx.x >> 6, chunk = blockIdx.x & 63;
    const int g = l >> 4, b15 = l & 15;
    const int o0 = wv * 4;
    const int i0 = chunk * CTI;
    const bool act = (g < 2);
    const short8v z8 = {0, 0, 0, 0, 0, 0, 0, 0};

    // Vsum packed to bf16 pairs: 8 VGPRs
    uint2 vpk[4];
    if (ROUTED) {
        #pragma unroll
        for (int oo = 0; oo < 4; ++oo) {
            f32x4 Vf = *reinterpret_cast<const f32x4*>(
                Vfp + (((size_t)btile * 64 + o0 + oo) * 64 + l) * 4);
            vpk[oo].x = (unsigned)f2bf(Vf[0]) | ((unsigned)f2bf(Vf[1]) << 16);
            vpk[oo].y = (unsigned)f2bf(Vf[2]) | ((unsigned)f2bf(Vf[3]) << 16);
        }
    }

    f32x4 s[4];
    #pragma unroll
    for (int oo = 0; oo < 4; ++oo) s[oo] = (f32x4){0.f, 0.f, 0.f, 0.f};

    // DMA IPB consecutive i-slices (32 KB): 2 rounds x 16 waves x 64 lanes x 16 B
    #define STAGE2(buf, ibase)                                                    \
    {                                                                             \
        const ushort8v* srcb = reinterpret_cast<const ushort8v*>(                 \
            Wp + (size_t)(ibase) * 8192);                                         \
        _Pragma("unroll")                                                         \
        for (int r = 0; r < 2; ++r)                                               \
            __builtin_amdgcn_global_load_lds(                                     \
                (gu32*)(srcb + (r * 1024 + wv * 64 + l)),                         \
                (lu32*)&wlds[buf][(size_t)(r * 1024 + wv * 64) * 8], 16, 0, 0);   \
    }

    // B-frag: plane = g (0=hi, 1=lo); zero for g>=2
    #define LOADB(i) (*reinterpret_cast<const short8v*>(                          \
        xp + (((size_t)(i) * 2 + g) * 64 + btile * 16 + b15) * 8))

    STAGE2(0, i0);
    short8v Bf0 = z8, Bf1 = z8;
    if (act) { Bf0 = LOADB(i0); Bf1 = LOADB(i0 + 1); }
    __syncthreads();   // prologue DMA complete

    const int aoffbase = b15 * 8;

    int cur = 0;
    for (int st = 0; st < NSTEP; ++st) {
        int nxt = cur + 1; if (nxt == 3) nxt = 0;
        // prefetch next 2 slices into the THIRD buffer; drains at this barrier
        short8v Bn0 = Bf0, Bn1 = Bf1;
        if (st + 1 < NSTEP) {
            STAGE2(nxt, i0 + (st + 1) * IPB);
            if (act) {
                Bn0 = LOADB(i0 + (st + 1) * IPB);
                Bn1 = LOADB(i0 + (st + 1) * IPB + 1);
            }
        }

        if (!ROUTED) {
            #pragma unroll
            for (int oo = 0; oo < 4; ++oo) {
                short8v Af0 = z8, Af1 = z8;
                if (act) {
                    const int ao = (o0 + oo) * 128 + aoffbase;
                    Af0 = *reinterpret_cast<const short8v*>(&wlds[cur][0] + ao);
                    Af1 = *reinterpret_cast<const short8v*>(&wlds[cur][8192] + ao);
                }
                s[oo] = __builtin_amdgcn_mfma_f32_16x16x32_bf16(Af0, Bf0, s[oo], 0, 0, 0);
                s[oo] = __builtin_amdgcn_mfma_f32_16x16x32_bf16(Af1, Bf1, s[oo], 0, 0, 0);
            }
            __syncthreads();   // DMA(next) complete
        } else {
            // ---- pre-barrier: logits only; u NOT kept across the barrier ----
            float lg0[4], lg1[4];
            float Zp0 = 0.f, Zp1 = 0.f;
            #pragma unroll
            for (int oo = 0; oo < 4; ++oo) {
                short8v Af0 = z8, Af1 = z8;
                if (act) {
                    const int ao = (o0 + oo) * 128 + aoffbase;
                    Af0 = *reinterpret_cast<const short8v*>(&wlds[cur][0] + ao);
                    Af1 = *reinterpret_cast<const short8v*>(&wlds[cur][8192] + ao);
                }
                f32x4 zz = {0.f, 0.f, 0.f, 0.f};
                f32x4 u0 = __builtin_amdgcn_mfma_f32_16x16x32_bf16(Af0, Bf0, zz, 0, 0, 0);
                f32x4 u1 = __builtin_amdgcn_mfma_f32_16x16x32_bf16(Af1, Bf1, zz, 0, 0, 0);
                float p0 = u0[0] * lo16f(vpk[oo].x);
                p0 = fmaf(u0[1], hi16f(vpk[oo].x), p0);
                p0 = fmaf(u0[2], lo16f(vpk[oo].y), p0);
                p0 = fmaf(u0[3], hi16f(vpk[oo].y), p0);
                float p1 = u1[0] * lo16f(vpk[oo].x);
                p1 = fmaf(u1[1], hi16f(vpk[oo].x), p1);
                p1 = fmaf(u1[2], lo16f(vpk[oo].y), p1);
                p1 = fmaf(u1[3], hi16f(vpk[oo].y), p1);
                p0 += __shfl_xor(p0, 16, 64);  p1 += __shfl_xor(p1, 16, 64);
                p0 += __shfl_xor(p0, 32, 64);  p1 += __shfl_xor(p1, 32, 64);
                float e0 = __expf(p0), e1 = __expf(p1);   // |logit| <= ~1.2
                lg0[oo] = e0; lg1[oo] = e1;
                Zp0 += e0; Zp1 += e1;
            }
            if (l < 16) {
                zbuf[st & 1][0][wv * 16 + l] = Zp0;
                zbuf[st & 1][1][wv * 16 + l] = Zp1;
            }
            __syncthreads();                   // Z visible; DMA(next) drained
            float Z0 = zbuf[st & 1][0][b15];
            float Z1 = zbuf[st & 1][1][b15];
            #pragma unroll
            for (int w2 = 1; w2 < 16; ++w2) {
                Z0 += zbuf[st & 1][0][w2 * 16 + b15];
                Z1 += zbuf[st & 1][1][w2 * 16 + b15];
            }
            float rz0 = 1.0f / Z0, rz1 = 1.0f / Z1;
            // ---- post-barrier: RECOMPUTE u from wlds[cur] (intact: next DMA
            // went to nxt; buffer cur is not re-staged until step st+2, which
            // all waves reach only after barrier st+1) and accumulate ----
            #pragma unroll
            for (int oo = 0; oo < 4; ++oo) {
                short8v Af0 = z8, Af1 = z8;
                if (act) {
                    const int ao = (o0 + oo) * 128 + aoffbase;
                    Af0 = *reinterpret_cast<const short8v*>(&wlds[cur][0] + ao);
                    Af1 = *reinterpret_cast<const short8v*>(&wlds[cur][8192] + ao);
                }
                f32x4 zz = {0.f, 0.f, 0.f, 0.f};
                f32x4 u0 = __builtin_amdgcn_mfma_f32_16x16x32_bf16(Af0, Bf0, zz, 0, 0, 0);
                f32x4 u1 = __builtin_amdgcn_mfma_f32_16x16x32_bf16(Af1, Bf1, zz, 0, 0, 0);
                float c0 = lg0[oo] * rz0;
                float c1 = lg1[oo] * rz1;
                s[oo][0] = fmaf(c0, u0[0], fmaf(c1, u1[0], s[oo][0]));
                s[oo][1] = fmaf(c0, u0[1], fmaf(c1, u1[1], s[oo][1]));
                s[oo][2] = fmaf(c0, u0[2], fmaf(c1, u1[2], s[oo][2]));
                s[oo][3] = fmaf(c0, u0[3], fmaf(c1, u1[3], s[oo][3]));
            }
        }
        Bf0 = Bn0; Bf1 = Bn1;
        cur = nxt;
    }

    // bf16 partials: [chunk][btile][o][l][4k], 8 B/lane coalesced
    const float fin = ROUTED ? 1.0f : (1.0f / 64.0f);
    #pragma unroll
    for (int oo = 0; oo < 4; ++oo) {
        f32x4 vv = s[oo] * fin;
        uint2 pk;
        pk.x = (unsigned)f2bf(vv[0]) | ((unsigned)f2bf(vv[1]) << 16);
        pk.y = (unsigned)f2bf(vv[2]) | ((unsigned)f2bf(vv[3]) << 16);
        *reinterpret_cast<uint2*>(spart +
            ((((size_t)chunk * 4 + btile) * 64 + (o0 + oo)) * 64 + l) * 4) = pk;
    }
    #undef STAGE2
    #undef LOADB
}

// Sum CNCH bf16 chunk-partials, squash, update Vfp / write out.
// Grid 256 blocks (one (btile,o) pair) x 256 thr: l = t&63, cq = t>>6.
template<int MODE>
__global__ __launch_bounds__(256)
void reduce2(const unsigned short* __restrict__ spart, float* __restrict__ Vfp,
             float* __restrict__ out) {
    __shared__ f32x4 red[256];
    const int t = threadIdx.x;
    const int l = t & 63, cq = t >> 6;
    const int pair = blockIdx.x;               // btile*64 + o
    const int btile = pair >> 6, o = pair & 63;

    f32x4 acc = {0.f, 0.f, 0.f, 0.f};
    const unsigned short* base = spart + (((size_t)btile * 64 + o) * 64 + l) * 4;
    for (int c = cq * (CNCH/4); c < (cq + 1) * (CNCH/4); ++c) {
        uint2 w = *reinterpret_cast<const uint2*>(base + (size_t)c * 65536);
        acc[0] += lo16f(w.x); acc[1] += hi16f(w.x);
        acc[2] += lo16f(w.y); acc[3] += hi16f(w.y);
    }
    red[t] = acc;
    __syncthreads();
    if (cq == 0) {
        acc = red[l] + red[64 + l] + red[128 + l] + red[192 + l];
        float n2 = acc[0]*acc[0] + acc[1]*acc[1] + acc[2]*acc[2] + acc[3]*acc[3];
        n2 += __shfl_xor(n2, 16, 64);
        n2 += __shfl_xor(n2, 32, 64);
        const float scale = n2 / (1.0f + n2) / sqrtf(n2 + 1e-7f);
        f32x4 v = acc * scale;
        float* vp = Vfp + (((size_t)btile * 64 + o) * 64 + l) * 4;
        if (MODE == 0) {
            *reinterpret_cast<f32x4*>(vp) = v;
        } else if (MODE == 1) {
            f32x4 old = *reinterpret_cast<const f32x4*>(vp);
            *reinterpret_cast<f32x4*>(vp) = old + v;
        } else {
            const int b = btile * 16 + (l & 15), gq = l >> 4;
            *reinterpret_cast<f32x4*>(out + (((size_t)b * 64 + o) * 16 + gq * 4)) = v;
        }
    }
}

// ------------------------- round-5 fallback (small ws, proven) -------------------------
#define FTI 18
#define FNCH 64

__device__ __forceinline__ void load_lds16(const float4* gp, float4* lp) {
    __builtin_amdgcn_global_load_lds((gu32*)gp, (lu32*)lp, 16, 0, 0);
}
__device__ __forceinline__ float rfl(float v) {
    return __builtin_bit_cast(float, __builtin_amdgcn_readfirstlane(__builtin_bit_cast(int, v)));
}

template<bool UNIFORM>
__global__ __launch_bounds__(256, 2)
void caps_route_fb(const float* __restrict__ x, const float* __restrict__ W,
                   const float* __restrict__ Vsum, float* __restrict__ s_out) {
    __shared__ float4 wlds[2][2048];
    __shared__ float4 xlds[8 * FTI * 2];
    const int t = threadIdx.x;
    const int w = t >> 6, o = t & 63;
    const int chunk = blockIdx.x % FNCH, bblk = blockIdx.x / FNCH;
    const int i0 = chunk * FTI, bbase = bblk * 8 + w * 2;
    const float4* __restrict__ xg = (const float4*)x;
    const float4* __restrict__ Wg = (const float4*)W;
    for (int e = t; e < 8 * FTI * 2; e += 256) {
        int bb = e / (FTI * 2), r = e % (FTI * 2);
        xlds[e] = xg[((bblk * 8 + bb) * 1152 + i0 + (r >> 1)) * 2 + (r & 1)];
    }
    const float4* wsrc = Wg + (size_t)o * 36864 + (size_t)i0 * 32 + w * 8;
    #pragma unroll
    for (int r = 0; r < 8; ++r) load_lds16(wsrc + r, &wlds[0][(w * 8 + r) * 64]);
    float vsf[2][16];
    if (!UNIFORM) {
        const float4* vg = (const float4*)Vsum;
        #pragma unroll
        for (int ll = 0; ll < 2; ++ll)
            #pragma unroll
            for (int q = 0; q < 4; ++q) {
                float4 v = vg[((size_t)(bbase + ll) * 64 + o) * 4 + q];
                vsf[ll][q*4+0] = v.x; vsf[ll][q*4+1] = v.y;
                vsf[ll][q*4+2] = v.z; vsf[ll][q*4+3] = v.w;
            }
    }
    float sacc[2][16];
    #pragma unroll
    for (int ll = 0; ll < 2; ++ll)
        #pragma unroll
        for (int k = 0; k < 16; ++k) sacc[ll][k] = 0.0f;
    for (int ii = 0; ii < FTI; ++ii) {
        const int cur = ii & 1;
        __syncthreads();
        if (ii + 1 < FTI) {
            const float4* ws = wsrc + (size_t)(ii + 1) * 32;
            #pragma unroll
            for (int r = 0; r < 8; ++r) load_lds16(ws + r, &wlds[cur ^ 1][(w * 8 + r) * 64]);
        }
        float4 A0 = xlds[(w*2+0)*(FTI*2) + ii*2 + 0];
        float4 B0 = xlds[(w*2+0)*(FTI*2) + ii*2 + 1];
        float4 A1 = xlds[(w*2+1)*(FTI*2) + ii*2 + 0];
        float4 B1 = xlds[(w*2+1)*(FTI*2) + ii*2 + 1];
        float xa0x=rfl(A0.x),xa0y=rfl(A0.y),xa0z=rfl(A0.z),xa0w=rfl(A0.w);
        float xb0x=rfl(B0.x),xb0y=rfl(B0.y),xb0z=rfl(B0.z),xb0w=rfl(B0.w);
        float xa1x=rfl(A1.x),xa1y=rfl(A1.y),xa1z=rfl(A1.z),xa1w=rfl(A1.w);
        float xb1x=rfl(B1.x),xb1y=rfl(B1.y),xb1z=rfl(B1.z),xb1w=rfl(B1.w);
        const float4* wb = wlds[cur];
        float u[2][16];
        float logit0 = 0.0f, logit1 = 0.0f;
        #pragma unroll
        for (int k = 0; k < 16; ++k) {
            float4 w0 = wb[(2*k  )*64 + o];
            float4 w1 = wb[(2*k+1)*64 + o];
            float uk0 = w0.x*xa0x; uk0=fmaf(w0.y,xa0y,uk0); uk0=fmaf(w0.z,xa0z,uk0);
            uk0=fmaf(w0.w,xa0w,uk0); uk0=fmaf(w1.x,xb0x,uk0); uk0=fmaf(w1.y,xb0y,uk0);
            uk0=fmaf(w1.z,xb0z,uk0); uk0=fmaf(w1.w,xb0w,uk0);
            float uk1 = w0.x*xa1x; uk1=fmaf(w0.y,xa1y,uk1); uk1=fmaf(w0.z,xa1z,uk1);
            uk1=fmaf(w0.w,xa1w,uk1); uk1=fmaf(w1.x,xb1x,uk1); uk1=fmaf(w1.y,xb1y,uk1);
            uk1=fmaf(w1.z,xb1z,uk1); uk1=fmaf(w1.w,xb1w,uk1);
            u[0][k]=uk0; u[1][k]=uk1;
            if (!UNIFORM) { logit0=fmaf(vsf[0][k],uk0,logit0); logit1=fmaf(vsf[1][k],uk1,logit1); }
        }
        float c0, c1;
        if (UNIFORM) { c0 = c1 = 1.0f/64.0f; }
        else {
            float m0=logit0, m1=logit1;
            #pragma unroll
            for (int d=32; d>=1; d>>=1) { m0=fmaxf(m0,__shfl_xor(m0,d,64)); m1=fmaxf(m1,__shfl_xor(m1,d,64)); }
            float e0=__expf(logit0-m0), e1=__expf(logit1-m1);
            float s0=e0, s1=e1;
            #pragma unroll
            for (int d=32; d>=1; d>>=1) { s0+=__shfl_xor(s0,d,64); s1+=__shfl_xor(s1,d,64); }
            c0=e0/s0; c1=e1/s1;
        }
        #pragma unroll
        for (int k = 0; k < 16; ++k) {
            sacc[0][k]=fmaf(c0,u[0][k],sacc[0][k]);
            sacc[1][k]=fmaf(c1,u[1][k],sacc[1][k]);
        }
    }
    #pragma unroll
    for (int ll = 0; ll < 2; ++ll) {
        float4* sp = (float4*)s_out + (((size_t)chunk * 64 + (bbase + ll)) * 64 + o) * 4;
        sp[0]=make_float4(sacc[ll][0],sacc[ll][1],sacc[ll][2],sacc[ll][3]);
        sp[1]=make_float4(sacc[ll][4],sacc[ll][5],sacc[ll][6],sacc[ll][7]);
        sp[2]=make_float4(sacc[ll][8],sacc[ll][9],sacc[ll][10],sacc[ll][11]);
        sp[3]=make_float4(sacc[ll][12],sacc[ll][13],sacc[ll][14],sacc[ll][15]);
    }
}

template<int MODE>
__global__ __launch_bounds__(256)
void reduce_squash_fb(const float* __restrict__ sp, float* __restrict__ Vs, float* __restrict__ out) {
    const int t = threadIdx.x;
    const int p = t >> 4, q = t & 15;
    const int pair = blockIdx.x * 16 + p;
    const int b = pair >> 6, o = pair & 63;
    float acc[16];
    #pragma unroll
    for (int k = 0; k < 16; ++k) acc[k] = 0.0f;
    const float4* base = (const float4*)sp;
    for (int c = q * (FNCH/16); c < (q + 1) * (FNCH/16); ++c) {
        const float4* pptr = base + (((size_t)c * 64 + b) * 64 + o) * 4;
        float4 v0=pptr[0],v1=pptr[1],v2=pptr[2],v3=pptr[3];
        acc[0]+=v0.x;acc[1]+=v0.y;acc[2]+=v0.z;acc[3]+=v0.w;
        acc[4]+=v1.x;acc[5]+=v1.y;acc[6]+=v1.z;acc[7]+=v1.w;
        acc[8]+=v2.x;acc[9]+=v2.y;acc[10]+=v2.z;acc[11]+=v2.w;
        acc[12]+=v3.x;acc[13]+=v3.y;acc[14]+=v3.z;acc[15]+=v3.w;
    }
    #pragma unroll
    for (int d = 1; d < 16; d <<= 1)
        #pragma unroll
        for (int k = 0; k < 16; ++k) acc[k] += __shfl_xor(acc[k], d, 64);
    if (q == 0) {
        float n2 = 0.0f;
        #pragma unroll
        for (int k = 0; k < 16; ++k) n2 = fmaf(acc[k], acc[k], n2);
        const float scale = n2 / (1.0f + n2) / sqrtf(n2 + 1e-7f);
        if (MODE == 0) {
            float4* vf = (float4*)Vs + (size_t)pair * 4;
            #pragma unroll
            for (int r = 0; r < 4; ++r)
                vf[r] = make_float4(scale*acc[r*4+0],scale*acc[r*4+1],scale*acc[r*4+2],scale*acc[r*4+3]);
        } else if (MODE == 1) {
            float4* vf = (float4*)Vs + (size_t)pair * 4;
            #pragma unroll
            for (int r = 0; r < 4; ++r) {
                float4 v = vf[r];
                v.x=fmaf(scale,acc[r*4+0],v.x); v.y=fmaf(scale,acc[r*4+1],v.y);
                v.z=fmaf(scale,acc[r*4+2],v.z); v.w=fmaf(scale,acc[r*4+3],v.w);
                vf[r] = v;
            }
        } else {
            float4* of = (float4*)out + (size_t)pair * 4;
            #pragma unroll
            for (int r = 0; r < 4; ++r)
                of[r] = make_float4(scale*acc[r*4+0],scale*acc[r*4+1],scale*acc[r*4+2],scale*acc[r*4+3]);
        }
    }
}
// -----------------------------------------------------------------------------

extern "C" void kernel_launch(void* const* d_in, const int* in_sizes, int n_in,
                              void* d_out, int out_size, void* d_ws, size_t ws_size,
                              hipStream_t stream) {
    const float* x = (const float*)d_in[0];   // [64,1152,8]
    const float* W = (const float*)d_in[1];   // [64,1152,16,8]
    float* out = (float*)d_out;               // [64,64,16]

    float* Vfp = (float*)d_ws;                                       // 65536 f32
    unsigned short* spart = (unsigned short*)(Vfp + 65536);          // CNCH*65536 bf16
    unsigned short* Wp = spart + (size_t)CNCH * 65536;               // hi-only
    unsigned short* xpp = Wp + (size_t)1152 * 64 * 128;
    const size_t need_full = (size_t)65536 * 4
        + ((size_t)CNCH * 65536 + (size_t)1152 * 64 * 128 + (size_t)1152 * 2 * 512) * 2;

    if (ws_size >= need_full) {
        xform<<<4608 + 288, 256, 0, stream>>>(W, x, Wp, xpp);
        caps_mfma<0><<<256, 1024, 0, stream>>>(Wp, xpp, Vfp, spart);
        reduce2<0><<<256, 256, 0, stream>>>(spart, Vfp, out);
        caps_mfma<1><<<256, 1024, 0, stream>>>(Wp, xpp, Vfp, spart);
        reduce2<1><<<256, 256, 0, stream>>>(spart, Vfp, out);
        caps_mfma<1><<<256, 1024, 0, stream>>>(Wp, xpp, Vfp, spart);
        reduce2<2><<<256, 256, 0, stream>>>(spart, Vfp, out);
    } else {
        // proven round-5 path (needs ~17 MB)
        float* Vs = (float*)d_ws;
        float* sp = Vs + 65536;
        dim3 grid(8 * FNCH), blk(256);
        dim3 rg(256), rb(256);
        caps_route_fb<true ><<<grid, blk, 0, stream>>>(x, W, nullptr, sp);
        reduce_squash_fb<0><<<rg, rb, 0, stream>>>(sp, Vs, out);
        caps_route_fb<false><<<grid, blk, 0, stream>>>(x, W, Vs, sp);
        reduce_squash_fb<1><<<rg, rb, 0, stream>>>(sp, Vs, out);
        caps_route_fb<false><<<grid, blk, 0, stream>>>(x, W, Vs, sp);
        reduce_squash_fb<2><<<rg, rb, 0, stream>>>(sp, Vs, out);
    }
}

// Round 19
// 88.206 us; speedup vs baseline: 3.2646x; 1.1669x over previous
//
#include <hip/hip_runtime.h>
#include <math.h>

// B=64, N_in=1152, K_in=8, N_out=64, K_out=16, ITER=3
// BEST-PROVEN (round 15, 88.2 us): MFMA path with W in bf16-HI ONLY:
// slots 0-7 = Whi*xhi, 8-15 = Whi*xlo, 16-31 = zeroed (A and B both zero).
// x hi/lo split -> x at fp32 fidelity; W rounding ~3e-4 (absmax 9.8e-4 vs
// threshold 4.5e-3). 1024-thr blocks (16 waves, 4 o/wave); 2 i-slices per
// LDS step (32 KB, double-buffered DMA) -> 9 barriers/pass; bf16 partials.
// Reverted here after r16 (cooperative fusion: compiler caps 1024-thr kernels
// at 64 VGPR -> spill), r17 (512-thr: occupancy halved), r18 (recompute-u:
// serial MFMA latency tail) all regressed.

#define CTI 18        // i per chunk
#define IPB 2         // i per buffer step
#define NSTEP 9       // CTI / IPB
#define CNCH 64       // 1152 / CTI

typedef __attribute__((ext_vector_type(8))) short short8v;
typedef __attribute__((ext_vector_type(8))) unsigned short ushort8v;
typedef __attribute__((ext_vector_type(4))) float f32x4;

typedef const __attribute__((address_space(1))) unsigned int gu32;
typedef __attribute__((address_space(3))) unsigned int lu32;

__device__ __forceinline__ unsigned short f2bf(float f) {   // RTNE
    unsigned u = __builtin_bit_cast(unsigned, f);
    u = u + 0x7FFFu + ((u >> 16) & 1u);
    return (unsigned short)(u >> 16);
}
__device__ __forceinline__ float bf2f(unsigned short h) {
    unsigned u = ((unsigned)h) << 16;
    return __builtin_bit_cast(float, u);
}
__device__ __forceinline__ float lo16f(unsigned u) {
    return __builtin_bit_cast(float, u << 16);
}
__device__ __forceinline__ float hi16f(unsigned u) {
    return __builtin_bit_cast(float, u & 0xFFFF0000u);
}

// W[o][i][k][j] f32 -> Wp[i][o][k][j] bf16 (HI only, 18.9 MB);
// x[b][i][j] f32 -> xp[i][p][b][j] bf16 hi/lo.
__global__ __launch_bounds__(256)
void xform(const float* __restrict__ W, const float* __restrict__ x,
           unsigned short* __restrict__ Wp, unsigned short* __restrict__ xpp) {
    const int bid = blockIdx.x;
    if (bid < 4608) {
        int tid = bid * 256 + threadIdx.x;          // 1152*64*16
        int k = tid & 15, o = (tid >> 4) & 63, i = tid >> 10;
        const float4* src = (const float4*)(W + (((size_t)o * 1152 + i) * 16 + k) * 8);
        float4 v0 = src[0], v1 = src[1];
        float vf[8] = {v0.x, v0.y, v0.z, v0.w, v1.x, v1.y, v1.z, v1.w};
        ushort8v hi;
        #pragma unroll
        for (int j = 0; j < 8; ++j) hi[j] = f2bf(vf[j]);
        *reinterpret_cast<ushort8v*>(Wp + (((size_t)i * 64 + o) * 16 + k) * 8) = hi;
    } else {
        int tid = (bid - 4608) * 256 + threadIdx.x; // 1152*64
        int b = tid & 63, i = tid >> 6;
        const float4* src = (const float4*)(x + ((size_t)b * 1152 + i) * 8);
        float4 v0 = src[0], v1 = src[1];
        float vf[8] = {v0.x, v0.y, v0.z, v0.w, v1.x, v1.y, v1.z, v1.w};
        ushort8v hi, lo;
        #pragma unroll
        for (int j = 0; j < 8; ++j) {
            unsigned short h = f2bf(vf[j]);
            hi[j] = h;
            lo[j] = f2bf(vf[j] - bf2f(h));
        }
        size_t base = ((size_t)i * 2) * 512 + (size_t)b * 8;
        *reinterpret_cast<ushort8v*>(xpp + base)       = hi;
        *reinterpret_cast<ushort8v*>(xpp + base + 512) = lo;
    }
}

// Routing pass. Grid 256 = btile(4) x chunk(64); btile-sharers of a chunk
// differ by 64 in blockIdx -> same XCD L2. Block: 1024 thr = 16 waves;
// wave wv owns o = wv*4..+4; lanes: col b = l&15 (= A-row k), group g = l>>4.
// Slot map (K=32): 0-7 Whi*xhi, 8-15 Whi*xlo, 16-31 zero (A=B=0 for g>=2).
// Wp staged 2 i-slices (32 KB) per step, double-buffered; ONE barrier/step.
template<int ROUTED>
__global__ __launch_bounds__(1024, 4)
void caps_mfma(const unsigned short* __restrict__ Wp,
               const unsigned short* __restrict__ xp,
               const float* __restrict__ Vfp,
               unsigned short* __restrict__ spart) {
    __shared__ unsigned short wlds[2][IPB * 8192];    // 2 x 32 KB (hi only)
    __shared__ float zbuf[2][IPB][256];               // [parity][sub-i][wave*16+b15]

    const int t = threadIdx.x;
    const int wv = t >> 6, l = t & 63;
    const int btile = blockIdx.x >> 6, chunk = blockIdx.x & 63;
    const int g = l >> 4, b15 = l & 15;
    const int o0 = wv * 4;
    const int i0 = chunk * CTI;
    const bool act = (g < 2);                 // lanes supplying nonzero slots

    // Vsum packed to bf16 pairs: 8 VGPRs
    uint2 vpk[4];
    if (ROUTED) {
        #pragma unroll
        for (int oo = 0; oo < 4; ++oo) {
            f32x4 Vf = *reinterpret_cast<const f32x4*>(
                Vfp + (((size_t)btile * 64 + o0 + oo) * 64 + l) * 4);
            vpk[oo].x = (unsigned)f2bf(Vf[0]) | ((unsigned)f2bf(Vf[1]) << 16);
            vpk[oo].y = (unsigned)f2bf(Vf[2]) | ((unsigned)f2bf(Vf[3]) << 16);
        }
    }

    f32x4 s[4];
    #pragma unroll
    for (int oo = 0; oo < 4; ++oo) s[oo] = (f32x4){0.f, 0.f, 0.f, 0.f};

    const short8v z8 = {0, 0, 0, 0, 0, 0, 0, 0};

    // DMA IPB consecutive i-slices (32 KB): 2 rounds x 16 waves x 64 lanes x 16 B
    #define STAGE2(buf, ibase)                                                    \
    {                                                                             \
        const ushort8v* srcb = reinterpret_cast<const ushort8v*>(                 \
            Wp + (size_t)(ibase) * 8192);                                         \
        _Pragma("unroll")                                                         \
        for (int r = 0; r < 2; ++r)                                               \
            __builtin_amdgcn_global_load_lds(                                     \
                (gu32*)(srcb + (r * 1024 + wv * 64 + l)),                         \
                (lu32*)&wlds[buf][(size_t)(r * 1024 + wv * 64) * 8], 16, 0, 0);   \
    }

    // B-frag for sub-i at global index i: plane = g (0=hi, 1=lo); zero for g>=2
    #define LOADB(i) (*reinterpret_cast<const short8v*>(                          \
        xp + (((size_t)(i) * 2 + g) * 64 + btile * 16 + b15) * 8))

    STAGE2(0, i0);
    short8v Bf0 = z8, Bf1 = z8;
    if (act) { Bf0 = LOADB(i0); Bf1 = LOADB(i0 + 1); }
    __syncthreads();   // prologue DMA complete

    // A-frag LDS offset (per sub-i base): row k = b15, j = 0..7 (16 B)
    const int aoffbase = b15 * 8;

    int cur = 0;
    for (int st = 0; st < NSTEP; ++st) {
        // prefetch next 2 slices; DMA drains at this step's single barrier
        short8v Bn0 = Bf0, Bn1 = Bf1;
        if (st + 1 < NSTEP) {
            STAGE2(cur ^ 1, i0 + (st + 1) * IPB);
            if (act) {
                Bn0 = LOADB(i0 + (st + 1) * IPB);
                Bn1 = LOADB(i0 + (st + 1) * IPB + 1);
            }
        }

        if (!ROUTED) {
            #pragma unroll
            for (int oo = 0; oo < 4; ++oo) {
                short8v Af0 = z8, Af1 = z8;
                if (act) {
                    const int ao = (o0 + oo) * 128 + aoffbase;
                    Af0 = *reinterpret_cast<const short8v*>(&wlds[cur][0] + ao);
                    Af1 = *reinterpret_cast<const short8v*>(&wlds[cur][8192] + ao);
                }
                s[oo] = __builtin_amdgcn_mfma_f32_16x16x32_bf16(Af0, Bf0, s[oo], 0, 0, 0);
                s[oo] = __builtin_amdgcn_mfma_f32_16x16x32_bf16(Af1, Bf1, s[oo], 0, 0, 0);
            }
            __syncthreads();   // DMA(next) complete + buffer-reuse safety
        } else {
            f32x4 u[IPB][4];
            float lg[IPB][4];
            float Zp0 = 0.f, Zp1 = 0.f;
            #pragma unroll
            for (int oo = 0; oo < 4; ++oo) {
                short8v Af0 = z8, Af1 = z8;
                if (act) {
                    const int ao = (o0 + oo) * 128 + aoffbase;
                    Af0 = *reinterpret_cast<const short8v*>(&wlds[cur][0] + ao);
                    Af1 = *reinterpret_cast<const short8v*>(&wlds[cur][8192] + ao);
                }
                f32x4 zz = {0.f, 0.f, 0.f, 0.f};
                u[0][oo] = __builtin_amdgcn_mfma_f32_16x16x32_bf16(Af0, Bf0, zz, 0, 0, 0);
                u[1][oo] = __builtin_amdgcn_mfma_f32_16x16x32_bf16(Af1, Bf1, zz, 0, 0, 0);

                float p0 = u[0][oo][0] * lo16f(vpk[oo].x);
                p0 = fmaf(u[0][oo][1], hi16f(vpk[oo].x), p0);
                p0 = fmaf(u[0][oo][2], lo16f(vpk[oo].y), p0);
                p0 = fmaf(u[0][oo][3], hi16f(vpk[oo].y), p0);
                float p1 = u[1][oo][0] * lo16f(vpk[oo].x);
                p1 = fmaf(u[1][oo][1], hi16f(vpk[oo].x), p1);
                p1 = fmaf(u[1][oo][2], lo16f(vpk[oo].y), p1);
                p1 = fmaf(u[1][oo][3], hi16f(vpk[oo].y), p1);
                p0 += __shfl_xor(p0, 16, 64);  p1 += __shfl_xor(p1, 16, 64);
                p0 += __shfl_xor(p0, 32, 64);  p1 += __shfl_xor(p1, 32, 64);
                // logits bounded (|logit| <= ~1.2): exp without max-subtraction
                float e0 = __expf(p0), e1 = __expf(p1);
                lg[0][oo] = e0; lg[1][oo] = e1;
                Zp0 += e0; Zp1 += e1;
            }
            if (l < 16) {
                zbuf[st & 1][0][wv * 16 + l] = Zp0;
                zbuf[st & 1][1][wv * 16 + l] = Zp1;
            }
            __syncthreads();                   // Z visible; DMA(next) drained
            float Z0 = zbuf[st & 1][0][b15];
            float Z1 = zbuf[st & 1][1][b15];
            #pragma unroll
            for (int w2 = 1; w2 < 16; ++w2) {
                Z0 += zbuf[st & 1][0][w2 * 16 + b15];
                Z1 += zbuf[st & 1][1][w2 * 16 + b15];
            }
            float rz0 = 1.0f / Z0, rz1 = 1.0f / Z1;
            #pragma unroll
            for (int oo = 0; oo < 4; ++oo) {
                float c0 = lg[0][oo] * rz0;
                float c1 = lg[1][oo] * rz1;
                s[oo][0] = fmaf(c0, u[0][oo][0], fmaf(c1, u[1][oo][0], s[oo][0]));
                s[oo][1] = fmaf(c0, u[0][oo][1], fmaf(c1, u[1][oo][1], s[oo][1]));
                s[oo][2] = fmaf(c0, u[0][oo][2], fmaf(c1, u[1][oo][2], s[oo][2]));
                s[oo][3] = fmaf(c0, u[0][oo][3], fmaf(c1, u[1][oo][3], s[oo][3]));
            }
        }
        Bf0 = Bn0; Bf1 = Bn1;
        cur ^= 1;
    }

    // bf16 partials: [chunk][btile][o][l][4k], 8 B/lane coalesced
    const float fin = ROUTED ? 1.0f : (1.0f / 64.0f);
    #pragma unroll
    for (int oo = 0; oo < 4; ++oo) {
        f32x4 vv = s[oo] * fin;
        uint2 pk;
        pk.x = (unsigned)f2bf(vv[0]) | ((unsigned)f2bf(vv[1]) << 16);
        pk.y = (unsigned)f2bf(vv[2]) | ((unsigned)f2bf(vv[3]) << 16);
        *reinterpret_cast<uint2*>(spart +
            ((((size_t)chunk * 4 + btile) * 64 + (o0 + oo)) * 64 + l) * 4) = pk;
    }
    #undef STAGE2
    #undef LOADB
}

// Sum CNCH bf16 chunk-partials, squash, update Vfp / write out.
// Grid 256 blocks (one (btile,o) pair) x 256 thr: l = t&63, cq = t>>6.
template<int MODE>
__global__ __launch_bounds__(256)
void reduce2(const unsigned short* __restrict__ spart, float* __restrict__ Vfp,
             float* __restrict__ out) {
    __shared__ f32x4 red[256];
    const int t = threadIdx.x;
    const int l = t & 63, cq = t >> 6;
    const int pair = blockIdx.x;               // btile*64 + o
    const int btile = pair >> 6, o = pair & 63;

    f32x4 acc = {0.f, 0.f, 0.f, 0.f};
    const unsigned short* base = spart + (((size_t)btile * 64 + o) * 64 + l) * 4;
    for (int c = cq * (CNCH/4); c < (cq + 1) * (CNCH/4); ++c) {
        uint2 w = *reinterpret_cast<const uint2*>(base + (size_t)c * 65536);
        acc[0] += lo16f(w.x); acc[1] += hi16f(w.x);
        acc[2] += lo16f(w.y); acc[3] += hi16f(w.y);
    }
    red[t] = acc;
    __syncthreads();
    if (cq == 0) {
        acc = red[l] + red[64 + l] + red[128 + l] + red[192 + l];
        float n2 = acc[0]*acc[0] + acc[1]*acc[1] + acc[2]*acc[2] + acc[3]*acc[3];
        n2 += __shfl_xor(n2, 16, 64);
        n2 += __shfl_xor(n2, 32, 64);
        const float scale = n2 / (1.0f + n2) / sqrtf(n2 + 1e-7f);
        f32x4 v = acc * scale;
        float* vp = Vfp + (((size_t)btile * 64 + o) * 64 + l) * 4;
        if (MODE == 0) {
            *reinterpret_cast<f32x4*>(vp) = v;
        } else if (MODE == 1) {
            f32x4 old = *reinterpret_cast<const f32x4*>(vp);
            *reinterpret_cast<f32x4*>(vp) = old + v;
        } else {
            const int b = btile * 16 + (l & 15), gq = l >> 4;
            *reinterpret_cast<f32x4*>(out + (((size_t)b * 64 + o) * 16 + gq * 4)) = v;
        }
    }
}

// ------------------------- round-5 fallback (small ws, proven) -------------------------
#define FTI 18
#define FNCH 64

__device__ __forceinline__ void load_lds16(const float4* gp, float4* lp) {
    __builtin_amdgcn_global_load_lds((gu32*)gp, (lu32*)lp, 16, 0, 0);
}
__device__ __forceinline__ float rfl(float v) {
    return __builtin_bit_cast(float, __builtin_amdgcn_readfirstlane(__builtin_bit_cast(int, v)));
}

template<bool UNIFORM>
__global__ __launch_bounds__(256, 2)
void caps_route_fb(const float* __restrict__ x, const float* __restrict__ W,
                   const float* __restrict__ Vsum, float* __restrict__ s_out) {
    __shared__ float4 wlds[2][2048];
    __shared__ float4 xlds[8 * FTI * 2];
    const int t = threadIdx.x;
    const int w = t >> 6, o = t & 63;
    const int chunk = blockIdx.x % FNCH, bblk = blockIdx.x / FNCH;
    const int i0 = chunk * FTI, bbase = bblk * 8 + w * 2;
    const float4* __restrict__ xg = (const float4*)x;
    const float4* __restrict__ Wg = (const float4*)W;
    for (int e = t; e < 8 * FTI * 2; e += 256) {
        int bb = e / (FTI * 2), r = e % (FTI * 2);
        xlds[e] = xg[((bblk * 8 + bb) * 1152 + i0 + (r >> 1)) * 2 + (r & 1)];
    }
    const float4* wsrc = Wg + (size_t)o * 36864 + (size_t)i0 * 32 + w * 8;
    #pragma unroll
    for (int r = 0; r < 8; ++r) load_lds16(wsrc + r, &wlds[0][(w * 8 + r) * 64]);
    float vsf[2][16];
    if (!UNIFORM) {
        const float4* vg = (const float4*)Vsum;
        #pragma unroll
        for (int ll = 0; ll < 2; ++ll)
            #pragma unroll
            for (int q = 0; q < 4; ++q) {
                float4 v = vg[((size_t)(bbase + ll) * 64 + o) * 4 + q];
                vsf[ll][q*4+0] = v.x; vsf[ll][q*4+1] = v.y;
                vsf[ll][q*4+2] = v.z; vsf[ll][q*4+3] = v.w;
            }
    }
    float sacc[2][16];
    #pragma unroll
    for (int ll = 0; ll < 2; ++ll)
        #pragma unroll
        for (int k = 0; k < 16; ++k) sacc[ll][k] = 0.0f;
    for (int ii = 0; ii < FTI; ++ii) {
        const int cur = ii & 1;
        __syncthreads();
        if (ii + 1 < FTI) {
            const float4* ws = wsrc + (size_t)(ii + 1) * 32;
            #pragma unroll
            for (int r = 0; r < 8; ++r) load_lds16(ws + r, &wlds[cur ^ 1][(w * 8 + r) * 64]);
        }
        float4 A0 = xlds[(w*2+0)*(FTI*2) + ii*2 + 0];
        float4 B0 = xlds[(w*2+0)*(FTI*2) + ii*2 + 1];
        float4 A1 = xlds[(w*2+1)*(FTI*2) + ii*2 + 0];
        float4 B1 = xlds[(w*2+1)*(FTI*2) + ii*2 + 1];
        float xa0x=rfl(A0.x),xa0y=rfl(A0.y),xa0z=rfl(A0.z),xa0w=rfl(A0.w);
        float xb0x=rfl(B0.x),xb0y=rfl(B0.y),xb0z=rfl(B0.z),xb0w=rfl(B0.w);
        float xa1x=rfl(A1.x),xa1y=rfl(A1.y),xa1z=rfl(A1.z),xa1w=rfl(A1.w);
        float xb1x=rfl(B1.x),xb1y=rfl(B1.y),xb1z=rfl(B1.z),xb1w=rfl(B1.w);
        const float4* wb = wlds[cur];
        float u[2][16];
        float logit0 = 0.0f, logit1 = 0.0f;
        #pragma unroll
        for (int k = 0; k < 16; ++k) {
            float4 w0 = wb[(2*k  )*64 + o];
            float4 w1 = wb[(2*k+1)*64 + o];
            float uk0 = w0.x*xa0x; uk0=fmaf(w0.y,xa0y,uk0); uk0=fmaf(w0.z,xa0z,uk0);
            uk0=fmaf(w0.w,xa0w,uk0); uk0=fmaf(w1.x,xb0x,uk0); uk0=fmaf(w1.y,xb0y,uk0);
            uk0=fmaf(w1.z,xb0z,uk0); uk0=fmaf(w1.w,xb0w,uk0);
            float uk1 = w0.x*xa1x; uk1=fmaf(w0.y,xa1y,uk1); uk1=fmaf(w0.z,xa1z,uk1);
            uk1=fmaf(w0.w,xa1w,uk1); uk1=fmaf(w1.x,xb1x,uk1); uk1=fmaf(w1.y,xb1y,uk1);
            uk1=fmaf(w1.z,xb1z,uk1); uk1=fmaf(w1.w,xb1w,uk1);
            u[0][k]=uk0; u[1][k]=uk1;
            if (!UNIFORM) { logit0=fmaf(vsf[0][k],uk0,logit0); logit1=fmaf(vsf[1][k],uk1,logit1); }
        }
        float c0, c1;
        if (UNIFORM) { c0 = c1 = 1.0f/64.0f; }
        else {
            float m0=logit0, m1=logit1;
            #pragma unroll
            for (int d=32; d>=1; d>>=1) { m0=fmaxf(m0,__shfl_xor(m0,d,64)); m1=fmaxf(m1,__shfl_xor(m1,d,64)); }
            float e0=__expf(logit0-m0), e1=__expf(logit1-m1);
            float s0=e0, s1=e1;
            #pragma unroll
            for (int d=32; d>=1; d>>=1) { s0+=__shfl_xor(s0,d,64); s1+=__shfl_xor(s1,d,64); }
            c0=e0/s0; c1=e1/s1;
        }
        #pragma unroll
        for (int k = 0; k < 16; ++k) {
            sacc[0][k]=fmaf(c0,u[0][k],sacc[0][k]);
            sacc[1][k]=fmaf(c1,u[1][k],sacc[1][k]);
        }
    }
    #pragma unroll
    for (int ll = 0; ll < 2; ++ll) {
        float4* sp = (float4*)s_out + (((size_t)chunk * 64 + (bbase + ll)) * 64 + o) * 4;
        sp[0]=make_float4(sacc[ll][0],sacc[ll][1],sacc[ll][2],sacc[ll][3]);
        sp[1]=make_float4(sacc[ll][4],sacc[ll][5],sacc[ll][6],sacc[ll][7]);
        sp[2]=make_float4(sacc[ll][8],sacc[ll][9],sacc[ll][10],sacc[ll][11]);
        sp[3]=make_float4(sacc[ll][12],sacc[ll][13],sacc[ll][14],sacc[ll][15]);
    }
}

template<int MODE>
__global__ __launch_bounds__(256)
void reduce_squash_fb(const float* __restrict__ sp, float* __restrict__ Vs, float* __restrict__ out) {
    const int t = threadIdx.x;
    const int p = t >> 4, q = t & 15;
    const int pair = blockIdx.x * 16 + p;
    const int b = pair >> 6, o = pair & 63;
    float acc[16];
    #pragma unroll
    for (int k = 0; k < 16; ++k) acc[k] = 0.0f;
    const float4* base = (const float4*)sp;
    for (int c = q * (FNCH/16); c < (q + 1) * (FNCH/16); ++c) {
        const float4* pptr = base + (((size_t)c * 64 + b) * 64 + o) * 4;
        float4 v0=pptr[0],v1=pptr[1],v2=pptr[2],v3=pptr[3];
        acc[0]+=v0.x;acc[1]+=v0.y;acc[2]+=v0.z;acc[3]+=v0.w;
        acc[4]+=v1.x;acc[5]+=v1.y;acc[6]+=v1.z;acc[7]+=v1.w;
        acc[8]+=v2.x;acc[9]+=v2.y;acc[10]+=v2.z;acc[11]+=v2.w;
        acc[12]+=v3.x;acc[13]+=v3.y;acc[14]+=v3.z;acc[15]+=v3.w;
    }
    #pragma unroll
    for (int d = 1; d < 16; d <<= 1)
        #pragma unroll
        for (int k = 0; k < 16; ++k) acc[k] += __shfl_xor(acc[k], d, 64);
    if (q == 0) {
        float n2 = 0.0f;
        #pragma unroll
        for (int k = 0; k < 16; ++k) n2 = fmaf(acc[k], acc[k], n2);
        const float scale = n2 / (1.0f + n2) / sqrtf(n2 + 1e-7f);
        if (MODE == 0) {
            float4* vf = (float4*)Vs + (size_t)pair * 4;
            #pragma unroll
            for (int r = 0; r < 4; ++r)
                vf[r] = make_float4(scale*acc[r*4+0],scale*acc[r*4+1],scale*acc[r*4+2],scale*acc[r*4+3]);
        } else if (MODE == 1) {
            float4* vf = (float4*)Vs + (size_t)pair * 4;
            #pragma unroll
            for (int r = 0; r < 4; ++r) {
                float4 v = vf[r];
                v.x=fmaf(scale,acc[r*4+0],v.x); v.y=fmaf(scale,acc[r*4+1],v.y);
                v.z=fmaf(scale,acc[r*4+2],v.z); v.w=fmaf(scale,acc[r*4+3],v.w);
                vf[r] = v;
            }
        } else {
            float4* of = (float4*)out + (size_t)pair * 4;
            #pragma unroll
            for (int r = 0; r < 4; ++r)
                of[r] = make_float4(scale*acc[r*4+0],scale*acc[r*4+1],scale*acc[r*4+2],scale*acc[r*4+3]);
        }
    }
}
// -----------------------------------------------------------------------------

extern "C" void kernel_launch(void* const* d_in, const int* in_sizes, int n_in,
                              void* d_out, int out_size, void* d_ws, size_t ws_size,
                              hipStream_t stream) {
    const float* x = (const float*)d_in[0];   // [64,1152,8]
    const float* W = (const float*)d_in[1];   // [64,1152,16,8]
    float* out = (float*)d_out;               // [64,64,16]

    float* Vfp = (float*)d_ws;                                       // 65536 f32
    unsigned short* spart = (unsigned short*)(Vfp + 65536);          // CNCH*65536 bf16
    unsigned short* Wp = spart + (size_t)CNCH * 65536;               // hi-only: 9.4M ushorts
    unsigned short* xpp = Wp + (size_t)1152 * 64 * 128;
    const size_t need_full = (size_t)65536 * 4
        + ((size_t)CNCH * 65536 + (size_t)1152 * 64 * 128 + (size_t)1152 * 2 * 512) * 2;

    if (ws_size >= need_full) {
        xform<<<4608 + 288, 256, 0, stream>>>(W, x, Wp, xpp);
        caps_mfma<0><<<256, 1024, 0, stream>>>(Wp, xpp, Vfp, spart);
        reduce2<0><<<256, 256, 0, stream>>>(spart, Vfp, out);
        caps_mfma<1><<<256, 1024, 0, stream>>>(Wp, xpp, Vfp, spart);
        reduce2<1><<<256, 256, 0, stream>>>(spart, Vfp, out);
        caps_mfma<1><<<256, 1024, 0, stream>>>(Wp, xpp, Vfp, spart);
        reduce2<2><<<256, 256, 0, stream>>>(spart, Vfp, out);
    } else {
        // proven round-5 path (needs ~17 MB)
        float* Vs = (float*)d_ws;
        float* sp = Vs + 65536;
        dim3 grid(8 * FNCH), blk(256);
        dim3 rg(256), rb(256);
        caps_route_fb<true ><<<grid, blk, 0, stream>>>(x, W, nullptr, sp);
        reduce_squash_fb<0><<<rg, rb, 0, stream>>>(sp, Vs, out);
        caps_route_fb<false><<<grid, blk, 0, stream>>>(x, W, Vs, sp);
        reduce_squash_fb<1><<<rg, rb, 0, stream>>>(sp, Vs, out);
        caps_route_fb<false><<<grid, blk, 0, stream>>>(x, W, Vs, sp);
        reduce_squash_fb<2><<<rg, rb, 0, stream>>>(sp, Vs, out);
    }
}